// Round 1
// baseline (3666.782 us; speedup 1.0000x reference)
//
#include <hip/hip_runtime.h>
#include <hip/hip_bf16.h>
#include <cstdio>
#include <cmath>

// Problem constants (B,T,C,NH fixed by the reference)
constexpr int   Bn = 4;
constexpr int   Tn = 2048;
constexpr int   Cn = 768;
constexpr float COEF  = 0.125f / 12.0f;   // SCALE / NH
constexpr float EPSZ  = 1e-8f;
constexpr float LNEPS = 1e-5f;
constexpr int   SPLITZ = 8;
#define NBTC ((size_t)Bn * Tn * Cn)

// cst[] indices: 0 Lam_tk, 1 lam_tk, 2 Lam_tbar, 3 lam_tbar, 4 Lam_tk1, 5 lam_tk1, 6 = 1.0
__global__ void prep_consts(const int* kp, float* cst) {
  if (threadIdx.x == 0 && blockIdx.x == 0) {
    float tk = 1.0f + (float)(*kp);
    float tb = tk + 0.5f;
    float t1 = tk + 1.0f;
    cst[0] = tk * tk * tk; cst[1] = 1.0f / cst[0];
    cst[2] = tb * tb * tb; cst[3] = 1.0f / cst[2];
    cst[4] = t1 * t1 * t1; cst[5] = 1.0f / cst[4];
    cst[6] = 1.0f;
  }
}

// LayerNorm of (alpha*src) with weight w, eps=1e-5, no bias. Also zeroes zbuf[row]
// for the stage's upcoming zpass (zbuf==nullptr for the final LN).
// NOTE: no __restrict__ on src/dst — the final LN runs in place.
__global__ void __launch_bounds__(256) ln_kernel(
    const float* src, const float* __restrict__ w,
    float* dst, float* zbuf, const float* __restrict__ cst, int alpha_idx) {
  const int row = blockIdx.x;
  const int tid = threadIdx.x;
  const float alpha = cst[alpha_idx];
  const float* x = src + (size_t)row * Cn;
  float v0 = alpha * x[tid];
  float v1 = alpha * x[tid + 256];
  float v2 = alpha * x[tid + 512];
  __shared__ float red[256];
  red[tid] = v0 + v1 + v2;
  __syncthreads();
  for (int off = 128; off > 0; off >>= 1) {
    if (tid < off) red[tid] += red[tid + off];
    __syncthreads();
  }
  const float m = red[0] * (1.0f / Cn);
  __syncthreads();
  const float d0 = v0 - m, d1 = v1 - m, d2 = v2 - m;
  red[tid] = d0 * d0 + d1 * d1 + d2 * d2;
  __syncthreads();
  for (int off = 128; off > 0; off >>= 1) {
    if (tid < off) red[tid] += red[tid + off];
    __syncthreads();
  }
  const float rstd = rsqrtf(red[0] * (1.0f / Cn) + LNEPS);
  float* y = dst + (size_t)row * Cn;
  y[tid]       = d0 * rstd * w[tid];
  y[tid + 256] = d1 * rstd * w[tid + 256];
  y[tid + 512] = d2 * rstd * w[tid + 512];
  if (tid == 0 && zbuf != nullptr) zbuf[row] = 0.0f;
}

// Causal gram pass: S = Xn Xn^T * COEF over a 64x64 tile, E = exp(clip(S)) stored
// to global (fp32), row-sums of E atomically accumulated into zbuf.
// grid = (SPLITZ, Tn/64, Bn); s-tiles strided by SPLITZ for load balance.
__global__ void __launch_bounds__(256) zpass_kernel(
    const float* __restrict__ Xn, float* __restrict__ E, float* __restrict__ zbuf) {
  const int b  = blockIdx.z;
  const int it = blockIdx.y;
  const int js = blockIdx.x;
  const int tid = threadIdx.x;
  const int tr = tid >> 4;          // 0..15  (t micro-rows)
  const int tc = tid & 15;          // 0..15  (s micro-cols)
  const int t0 = it * 64;
  const float* Xb = Xn + (size_t)b * Tn * Cn;
  float* Eb = E + (size_t)b * Tn * Tn;

  __shared__ float Qs[64][33];      // stride 33: conflict-free column reads
  __shared__ float Ks[64][33];

  const int lrow = tid >> 2;        // 0..63
  const int lcol = (tid & 3) * 8;   // 0,8,16,24

  float zacc[4] = {0.f, 0.f, 0.f, 0.f};

  for (int st = js; st <= it; st += SPLITZ) {
    const int s0 = st * 64;
    float acc[4][4] = {};
    for (int c0 = 0; c0 < Cn; c0 += 32) {
      const float* qsrc = Xb + (size_t)(t0 + lrow) * Cn + c0 + lcol;
      const float* ksrc = Xb + (size_t)(s0 + lrow) * Cn + c0 + lcol;
      const float4 q0 = *(const float4*)(qsrc);
      const float4 q1 = *(const float4*)(qsrc + 4);
      const float4 k0 = *(const float4*)(ksrc);
      const float4 k1 = *(const float4*)(ksrc + 4);
      __syncthreads();              // previous inner-loop reads done
      Qs[lrow][lcol+0]=q0.x; Qs[lrow][lcol+1]=q0.y; Qs[lrow][lcol+2]=q0.z; Qs[lrow][lcol+3]=q0.w;
      Qs[lrow][lcol+4]=q1.x; Qs[lrow][lcol+5]=q1.y; Qs[lrow][lcol+6]=q1.z; Qs[lrow][lcol+7]=q1.w;
      Ks[lrow][lcol+0]=k0.x; Ks[lrow][lcol+1]=k0.y; Ks[lrow][lcol+2]=k0.z; Ks[lrow][lcol+3]=k0.w;
      Ks[lrow][lcol+4]=k1.x; Ks[lrow][lcol+5]=k1.y; Ks[lrow][lcol+6]=k1.z; Ks[lrow][lcol+7]=k1.w;
      __syncthreads();
      #pragma unroll 8
      for (int kk = 0; kk < 32; ++kk) {
        float a[4], bb[4];
        #pragma unroll
        for (int i = 0; i < 4; ++i) a[i] = Qs[tr * 4 + i][kk];
        #pragma unroll
        for (int j = 0; j < 4; ++j) bb[j] = Ks[tc * 4 + j][kk];
        #pragma unroll
        for (int i = 0; i < 4; ++i)
          #pragma unroll
          for (int j = 0; j < 4; ++j)
            acc[i][j] += a[i] * bb[j];
      }
    }
    const int sgb = s0 + tc * 4;
    #pragma unroll
    for (int i = 0; i < 4; ++i) {
      const int tg = t0 + tr * 4 + i;
      float e[4];
      #pragma unroll
      for (int j = 0; j < 4; ++j) {
        float sV = acc[i][j] * COEF;
        sV = fminf(fmaxf(sV, -60.f), 60.f);
        e[j] = (sgb + j <= tg) ? __expf(sV) : 0.f;
        zacc[i] += e[j];
      }
      *(float4*)(Eb + (size_t)tg * Tn + sgb) = make_float4(e[0], e[1], e[2], e[3]);
    }
  }
  // reduce the 4 row partials across the 16 lanes sharing tr, then one atomic each
  #pragma unroll
  for (int i = 0; i < 4; ++i) {
    float v = zacc[i];
    v += __shfl_xor(v, 1);
    v += __shfl_xor(v, 2);
    v += __shfl_xor(v, 4);
    v += __shfl_xor(v, 8);
    if (tc == 0) atomicAdd(&zbuf[b * Tn + t0 + tr * 4 + i], v);
  }
}

// Finalize z (raw sum -> max(sum/T, EPS)) and compute sv = |p|^2 / (z^2 + EPS),
// p = cst[ps_idx] * Pisrc[row,:].
__global__ void __launch_bounds__(256) sv_kernel(
    const float* __restrict__ Pisrc, float* __restrict__ zbuf,
    float* __restrict__ sv, const float* __restrict__ cst, int ps_idx) {
  const int row = blockIdx.x;
  const int tid = threadIdx.x;
  const float* p = Pisrc + (size_t)row * Cn;
  const float v0 = p[tid], v1 = p[tid + 256], v2 = p[tid + 512];
  __shared__ float red[256];
  red[tid] = v0 * v0 + v1 * v1 + v2 * v2;
  __syncthreads();
  for (int off = 128; off > 0; off >>= 1) {
    if (tid < off) red[tid] += red[tid + off];
    __syncthreads();
  }
  if (tid == 0) {
    const float ps = cst[ps_idx];
    const float a = red[0] * ps * ps;
    const float zf = fmaxf(zbuf[row] * (1.0f / Tn), EPSZ);
    zbuf[row] = zf;
    sv[row] = a / (zf * zf + EPSZ);
  }
}

// core GEMM: dst = src*cst[ss_idx] + (tau*Lam/(2T)) * W @ Xn,
// W[t][s] = E[t][s] * (sv[t] + sv[s] - 2) formed on LDS store.
// grid = (Cn/64, Tn/64, Bn). NOTE: src/dst may alias (in-place stages).
__global__ void __launch_bounds__(256) corepass_kernel(
    const float* __restrict__ E, const float* __restrict__ Xn,
    const float* __restrict__ sv, const float* src, float* dst,
    const float* __restrict__ cst, int ss_idx, int lam_idx) {
  const int b  = blockIdx.z;
  const int it = blockIdx.y;
  const int ic = blockIdx.x;
  const int tid = threadIdx.x;
  const int tr = tid >> 4, tc = tid & 15;
  const int t0 = it * 64, c0 = ic * 64;
  const float* Eb  = E  + (size_t)b * Tn * Tn;
  const float* Xb  = Xn + (size_t)b * Tn * Cn;
  const float* svB = sv + b * Tn;

  __shared__ float As[64][65];
  __shared__ float Bs[64][65];

  const int lrow = tid >> 2;          // 0..63
  const int lcol = (tid & 3) * 16;    // 0,16,32,48
  const float st2 = svB[t0 + lrow] - 2.0f;

  float acc[4][4] = {};

  for (int st = 0; st <= it; ++st) {
    const int s0 = st * 64;
    float ee[16], xx[16], ssv[16];
    const float* ep = Eb  + (size_t)(t0 + lrow) * Tn + s0 + lcol;
    const float* xp = Xb  + (size_t)(s0 + lrow) * Cn + c0 + lcol;
    const float* sp = svB + s0 + lcol;
    #pragma unroll
    for (int q = 0; q < 4; ++q) {
      *(float4*)(ee  + 4 * q) = *(const float4*)(ep + 4 * q);
      *(float4*)(xx  + 4 * q) = *(const float4*)(xp + 4 * q);
      *(float4*)(ssv + 4 * q) = *(const float4*)(sp + 4 * q);
    }
    __syncthreads();                  // previous inner-loop reads done
    #pragma unroll
    for (int q = 0; q < 16; ++q) As[lrow][lcol + q] = ee[q] * (st2 + ssv[q]);
    #pragma unroll
    for (int q = 0; q < 16; ++q) Bs[lrow][lcol + q] = xx[q];
    __syncthreads();
    #pragma unroll 8
    for (int kk = 0; kk < 64; ++kk) {
      float a[4], x[4];
      #pragma unroll
      for (int i = 0; i < 4; ++i) a[i] = As[tr * 4 + i][kk];
      #pragma unroll
      for (int j = 0; j < 4; ++j) x[j] = Bs[kk][tc * 4 + j];
      #pragma unroll
      for (int i = 0; i < 4; ++i)
        #pragma unroll
        for (int j = 0; j < 4; ++j)
          acc[i][j] += a[i] * x[j];
    }
  }
  const float coef = 0.5f * cst[lam_idx] * (1.0f / (2.0f * Tn));
  const float ss = cst[ss_idx];
  #pragma unroll
  for (int i = 0; i < 4; ++i) {
    #pragma unroll
    for (int j = 0; j < 4; ++j) {
      const size_t off = ((size_t)b * Tn + t0 + tr * 4 + i) * Cn + c0 + tc * 4 + j;
      dst[off] = src[off] * ss + coef * acc[i][j];
    }
  }
}

// dst = s1 + 0.5*cst[lam_idx]*s2/z[row]   (velocity update; may run in place on s1)
__global__ void __launch_bounds__(256) velupd_kernel(
    const float* s1, const float* s2, const float* __restrict__ zb,
    float* dst, const float* __restrict__ cst, int lam_idx) {
  const int blk = blockIdx.x;
  const int row = blk / 3;                       // Cn = 3*256
  const size_t i = (size_t)row * Cn + (blk % 3) * 256 + threadIdx.x;
  const float vs = 0.5f * cst[lam_idx];
  dst[i] = s1[i] + vs * s2[i] / zb[row];
}

__global__ void __launch_bounds__(256) rot_kernel(
    float* X, float* Pi, float* bX, float* bPi, float c, float sn) {
  const size_t i = (size_t)blockIdx.x * 256 + threadIdx.x;
  const float x = X[i], p = Pi[i], bx = bX[i], bp = bPi[i];
  const float dX = x - bx, dPi = p - bp, sX = x + bx, sPi = p + bp;
  X[i]   = 0.5f * (sX + c * dX + sn * dPi);
  Pi[i]  = 0.5f * (sPi - sn * dX + c * dPi);
  bX[i]  = 0.5f * (sX - c * dX - sn * dPi);
  bPi[i] = 0.5f * (sPi + sn * dX - c * dPi);
}

extern "C" void kernel_launch(void* const* d_in, const int* in_sizes, int n_in,
                              void* d_out, int out_size, void* d_ws, size_t ws_size,
                              hipStream_t stream) {
  (void)in_sizes; (void)n_in; (void)out_size;
  const float* Xk  = (const float*)d_in[0];
  const float* Pk  = (const float*)d_in[1];
  const float* lw  = (const float*)d_in[2];
  const float* lvw = (const float*)d_in[3];
  const int*   kp  = (const int*)d_in[4];

  float* Xo = (float*)d_out;        // X state lives in d_out[0:BTC]
  float* Po = Xo + NBTC;            // Pi state lives in d_out[BTC:2BTC]

  char* wp = (char*)d_ws;
  float* bX  = (float*)wp; wp += NBTC * sizeof(float);
  float* bPi = (float*)wp; wp += NBTC * sizeof(float);
  float* Xn  = (float*)wp; wp += NBTC * sizeof(float);
  float* E   = (float*)wp; wp += (size_t)Bn * Tn * Tn * sizeof(float);
  float* zb  = (float*)wp; wp += (size_t)Bn * Tn * sizeof(float);
  float* sv  = (float*)wp; wp += (size_t)Bn * Tn * sizeof(float);
  float* cst = (float*)wp; wp += 256;
  const size_t need = (size_t)(wp - (char*)d_ws);
  if (ws_size < need) {
    fprintf(stderr, "[kernel] ws too small: %zu < %zu\n", ws_size, need);
    return;
  }

  const dim3 b256(256);
  const dim3 gLN(Bn * Tn);
  const dim3 gZ(SPLITZ, Tn / 64, Bn);
  const dim3 gCore(Cn / 64, Tn / 64, Bn);
  const dim3 gEW(Bn * Tn * 3);
  const float rc = (float)cos(2.0), rs = (float)sin(2.0);   // theta = 2*XI*h

  prep_consts<<<1, 1, 0, stream>>>(kp, cst);

  // ---- Stage A: X-side = Xk, p = Pk (lam*Lam = 1) ----
  ln_kernel<<<gLN, b256, 0, stream>>>(Xk, lw, Xn, zb, cst, 6);
  zpass_kernel<<<gZ, b256, 0, stream>>>(Xn, E, zb);
  sv_kernel<<<gLN, b256, 0, stream>>>(Pk, zb, sv, cst, 6);
  corepass_kernel<<<gCore, b256, 0, stream>>>(E, Xn, sv, Pk, Po, cst, 0, 0);   // Pi = Lam_tk*Pk + tau*Lam_tk*core
  velupd_kernel<<<gEW, b256, 0, stream>>>(Xk, Pk, zb, bX, cst, 6);             // bX = Xk + tau*Pk/z0

  // ---- Stage B: X-side = bX, Pi-side = Po ----
  ln_kernel<<<gLN, b256, 0, stream>>>(bX, lw, Xn, zb, cst, 6);
  zpass_kernel<<<gZ, b256, 0, stream>>>(Xn, E, zb);
  sv_kernel<<<gLN, b256, 0, stream>>>(Po, zb, sv, cst, 3);                     // p = lam_tbar*Pi
  velupd_kernel<<<gEW, b256, 0, stream>>>(Xk, Po, zb, Xo, cst, 3);             // X = Xk + tau*lam_tbar*Pi/z1
  corepass_kernel<<<gCore, b256, 0, stream>>>(E, Xn, sv, Pk, bPi, cst, 0, 2);  // bPi = Lam_tk*Pk + tau*Lam_tbar*core

  // ---- rotation mixing ----
  rot_kernel<<<gEW, b256, 0, stream>>>(Xo, Po, bX, bPi, rc, rs);

  // ---- Stage C: X-side = bX, Pi-side = Po ----
  ln_kernel<<<gLN, b256, 0, stream>>>(bX, lw, Xn, zb, cst, 6);
  zpass_kernel<<<gZ, b256, 0, stream>>>(Xn, E, zb);
  sv_kernel<<<gLN, b256, 0, stream>>>(Po, zb, sv, cst, 3);
  velupd_kernel<<<gEW, b256, 0, stream>>>(Xo, Po, zb, Xo, cst, 3);             // X += tau*lam_tbar*Pi/z2
  corepass_kernel<<<gCore, b256, 0, stream>>>(E, Xn, sv, bPi, bPi, cst, 6, 2); // bPi += tau*Lam_tbar*core

  // ---- Stage D: X-side = Xo, p = lam_tk1*bPi ----
  ln_kernel<<<gLN, b256, 0, stream>>>(Xo, lw, Xn, zb, cst, 6);
  zpass_kernel<<<gZ, b256, 0, stream>>>(Xn, E, zb);
  sv_kernel<<<gLN, b256, 0, stream>>>(bPi, zb, sv, cst, 5);
  corepass_kernel<<<gCore, b256, 0, stream>>>(E, Xn, sv, Po, Po, cst, 6, 4);   // Pi += tau*Lam_tk1*core

  // ---- Final: Pk1 = LN(lam_tk1 * Pi) * ln_v_w (in place on Po) ----
  ln_kernel<<<gLN, b256, 0, stream>>>(Po, lvw, Po, nullptr, cst, 5);
}

// Round 2
// 1701.268 us; speedup vs baseline: 2.1553x; 2.1553x over previous
//
#include <hip/hip_runtime.h>
#include <hip/hip_bf16.h>
#include <cstdio>
#include <cmath>

// Problem constants (B,T,C,NH fixed by the reference)
constexpr int   Bn = 4;
constexpr int   Tn = 2048;
constexpr int   Cn = 768;
constexpr float COEF  = 0.125f / 12.0f;   // SCALE / NH
constexpr float EPSZ  = 1e-8f;
constexpr float LNEPS = 1e-5f;
#define NBTC ((size_t)Bn * Tn * Cn)

typedef __bf16 bf16_t;
typedef bf16_t bf16x8 __attribute__((ext_vector_type(8)));
typedef float  f32x4  __attribute__((ext_vector_type(4)));

// cst[] indices: 0 Lam_tk, 1 lam_tk, 2 Lam_tbar, 3 lam_tbar, 4 Lam_tk1, 5 lam_tk1, 6 = 1.0
__global__ void prep_consts(const int* kp, float* cst) {
  if (threadIdx.x == 0 && blockIdx.x == 0) {
    float tk = 1.0f + (float)(*kp);
    float tb = tk + 0.5f;
    float t1 = tk + 1.0f;
    cst[0] = tk * tk * tk; cst[1] = 1.0f / cst[0];
    cst[2] = tb * tb * tb; cst[3] = 1.0f / cst[2];
    cst[4] = t1 * t1 * t1; cst[5] = 1.0f / cst[4];
    cst[6] = 1.0f;
  }
}

// LayerNorm of (alpha*src) with weight w -> hi/lo bf16 split outputs.
// Also zeroes zbuf[row] for the stage's upcoming zpass atomics.
__global__ void __launch_bounds__(256) ln_hl_kernel(
    const float* __restrict__ src, const float* __restrict__ w,
    bf16_t* __restrict__ outH, bf16_t* __restrict__ outL,
    float* __restrict__ zbuf, const float* __restrict__ cst, int alpha_idx) {
  const int row = blockIdx.x;
  const int tid = threadIdx.x;
  const float alpha = cst[alpha_idx];
  const float* x = src + (size_t)row * Cn;
  float v0 = alpha * x[tid];
  float v1 = alpha * x[tid + 256];
  float v2 = alpha * x[tid + 512];
  __shared__ float red[256];
  red[tid] = v0 + v1 + v2;
  __syncthreads();
  for (int off = 128; off > 0; off >>= 1) {
    if (tid < off) red[tid] += red[tid + off];
    __syncthreads();
  }
  const float m = red[0] * (1.0f / Cn);
  __syncthreads();
  const float d0 = v0 - m, d1 = v1 - m, d2 = v2 - m;
  red[tid] = d0 * d0 + d1 * d1 + d2 * d2;
  __syncthreads();
  for (int off = 128; off > 0; off >>= 1) {
    if (tid < off) red[tid] += red[tid + off];
    __syncthreads();
  }
  const float rstd = rsqrtf(red[0] * (1.0f / Cn) + LNEPS);
  const size_t base = (size_t)row * Cn;
  float f0 = d0 * rstd * w[tid];
  float f1 = d1 * rstd * w[tid + 256];
  float f2 = d2 * rstd * w[tid + 512];
  bf16_t h0 = (bf16_t)f0, h1 = (bf16_t)f1, h2 = (bf16_t)f2;
  outH[base + tid]       = h0;  outL[base + tid]       = (bf16_t)(f0 - (float)h0);
  outH[base + tid + 256] = h1;  outL[base + tid + 256] = (bf16_t)(f1 - (float)h1);
  outH[base + tid + 512] = h2;  outL[base + tid + 512] = (bf16_t)(f2 - (float)h2);
  if (tid == 0) zbuf[row] = 0.0f;
}

// Causal gram via split-bf16 MFMA: S = Xn Xn^T * COEF over a 64x64 tile.
// E = exp(clip(S)) stored fp32; row-sums of E atomically accumulated into zbuf.
// grid = (528 triangular tiles, Bn). No LDS: A/B frags read straight from
// global (row-major, k-contiguous) -> L1/L2 serve the reuse.
__global__ void __launch_bounds__(256) zpass_mfma(
    const bf16_t* __restrict__ XnH, const bf16_t* __restrict__ XnL,
    float* __restrict__ E, float* __restrict__ zbuf) {
  const int b = blockIdx.y;
  int l = blockIdx.x;
  int it = (int)((sqrtf(8.0f * (float)l + 1.0f) - 1.0f) * 0.5f);
  while ((it + 1) * (it + 2) / 2 <= l) ++it;
  while (it * (it + 1) / 2 > l) --it;
  const int st = l - it * (it + 1) / 2;
  const int t0 = it * 64, s0 = st * 64;

  const int tid  = threadIdx.x;
  const int lane = tid & 63;
  const int wv   = tid >> 6;        // wave 0..3 -> t-strip
  const int quad = lane >> 4;       // k-quad
  const int l15  = lane & 15;

  const bf16_t* XbH = XnH + (size_t)b * Tn * Cn;
  const bf16_t* XbL = XnL + (size_t)b * Tn * Cn;
  float* Eb = E + (size_t)b * Tn * Tn;

  const bf16_t* aH = XbH + (size_t)(t0 + wv * 16 + l15) * Cn;
  const bf16_t* aL = XbL + (size_t)(t0 + wv * 16 + l15) * Cn;
  const bf16_t* bH0 = XbH + (size_t)(s0 + l15) * Cn;
  const bf16_t* bL0 = XbL + (size_t)(s0 + l15) * Cn;

  f32x4 acc[4] = {};
  for (int c0 = 0; c0 < Cn; c0 += 32) {
    const int kb = c0 + quad * 8;
    bf16x8 ah = *(const bf16x8*)(aH + kb);
    bf16x8 al = *(const bf16x8*)(aL + kb);
    #pragma unroll
    for (int j = 0; j < 4; ++j) {
      bf16x8 bh = *(const bf16x8*)(bH0 + (size_t)(j * 16) * Cn + kb);
      bf16x8 bl = *(const bf16x8*)(bL0 + (size_t)(j * 16) * Cn + kb);
      acc[j] = __builtin_amdgcn_mfma_f32_16x16x32_bf16(ah, bh, acc[j], 0, 0, 0);
      acc[j] = __builtin_amdgcn_mfma_f32_16x16x32_bf16(al, bh, acc[j], 0, 0, 0);
      acc[j] = __builtin_amdgcn_mfma_f32_16x16x32_bf16(ah, bl, acc[j], 0, 0, 0);
    }
  }

  float zacc[4] = {0.f, 0.f, 0.f, 0.f};
  #pragma unroll
  for (int j = 0; j < 4; ++j) {
    const int col = s0 + j * 16 + l15;
    #pragma unroll
    for (int r = 0; r < 4; ++r) {
      const int row = t0 + wv * 16 + quad * 4 + r;
      float sV = acc[j][r] * COEF;
      sV = fminf(fmaxf(sV, -60.f), 60.f);
      const float e = (col <= row) ? __expf(sV) : 0.f;
      Eb[(size_t)row * Tn + col] = e;
      zacc[r] += e;
    }
  }
  #pragma unroll
  for (int r = 0; r < 4; ++r) {
    float v = zacc[r];
    v += __shfl_xor(v, 1);
    v += __shfl_xor(v, 2);
    v += __shfl_xor(v, 4);
    v += __shfl_xor(v, 8);
    if (l15 == 0) atomicAdd(&zbuf[b * Tn + t0 + wv * 16 + quad * 4 + r], v);
  }
}

// Finalize z (raw sum -> max(sum/T, EPS)) and compute sv = |p|^2 / (z^2 + EPS).
__global__ void __launch_bounds__(256) sv_kernel(
    const float* __restrict__ Pisrc, float* __restrict__ zbuf,
    float* __restrict__ sv, const float* __restrict__ cst, int ps_idx) {
  const int row = blockIdx.x;
  const int tid = threadIdx.x;
  const float* p = Pisrc + (size_t)row * Cn;
  const float v0 = p[tid], v1 = p[tid + 256], v2 = p[tid + 512];
  __shared__ float red[256];
  red[tid] = v0 * v0 + v1 * v1 + v2 * v2;
  __syncthreads();
  for (int off = 128; off > 0; off >>= 1) {
    if (tid < off) red[tid] += red[tid + off];
    __syncthreads();
  }
  if (tid == 0) {
    const float ps = cst[ps_idx];
    const float a = red[0] * ps * ps;
    const float zf = fmaxf(zbuf[row] * (1.0f / Tn), EPSZ);
    zbuf[row] = zf;
    sv[row] = a / (zf * zf + EPSZ);
  }
}

// core GEMM via split-bf16 MFMA: dst = src*cst[ss_idx] + (tau*Lam/(2T)) * W @ Xn,
// W[t][s] = E[t][s]*(sv[t]+sv[s]-2) built in-register (A operand, k=s contiguous).
// B operand (Xn[s][c], k=s) staged transposed in LDS per 32-s chunk.
// grid = (Cn/64, Tn/64, Bn). src/dst may alias.
__global__ void __launch_bounds__(256) corepass_mfma(
    const float* __restrict__ E,
    const bf16_t* __restrict__ XnH, const bf16_t* __restrict__ XnL,
    const float* __restrict__ sv, const float* src, float* dst,
    const float* __restrict__ cst, int ss_idx, int lam_idx) {
  const int b  = blockIdx.z;
  const int it = blockIdx.y;
  const int ic = blockIdx.x;
  const int t0 = it * 64, c0 = ic * 64;

  const int tid  = threadIdx.x;
  const int lane = tid & 63;
  const int wv   = tid >> 6;
  const int quad = lane >> 4;
  const int l15  = lane & 15;

  const float*  Eb  = E   + (size_t)b * Tn * Tn;
  const ushort* XbH = (const ushort*)(XnH + (size_t)b * Tn * Cn);
  const ushort* XbL = (const ushort*)(XnL + (size_t)b * Tn * Cn);
  const float*  svB = sv + b * Tn;

  __shared__ ushort XTh[64][40];    // [c][s] chunk, stride 40 (80B, 16B-aligned rows)
  __shared__ ushort XTl[64][40];

  const float* eRow = Eb + (size_t)(t0 + wv * 16 + l15) * Tn;
  const float  svt  = svB[t0 + wv * 16 + l15] - 2.0f;

  // staging mapping: thread covers c = sc4..sc4+3, s-pair sp
  const int sc4 = (tid & 15) * 4;
  const int sp  = tid >> 4;         // 0..15 -> s = 2sp, 2sp+1

  f32x4 acc[4] = {};
  const int chunks = (it + 1) * 2;
  for (int kc = 0; kc < chunks; ++kc) {
    const int sstart = kc * 32;
    // global staging loads (issued before the barrier)
    const int gs = sstart + sp * 2;
    const ushort* h0p = XbH + (size_t)gs * Cn + c0 + sc4;
    const ushort* l0p = XbL + (size_t)gs * Cn + c0 + sc4;
    const ushort4 H0 = *(const ushort4*)h0p;
    const ushort4 H1 = *(const ushort4*)(h0p + Cn);
    const ushort4 L0 = *(const ushort4*)l0p;
    const ushort4 L1 = *(const ushort4*)(l0p + Cn);

    // A-operand: W hi/lo built in-register
    const int sOff = sstart + quad * 8;
    const float4 e0  = *(const float4*)(eRow + sOff);
    const float4 e1  = *(const float4*)(eRow + sOff + 4);
    const float4 sv0 = *(const float4*)(svB + sOff);
    const float4 sv1 = *(const float4*)(svB + sOff + 4);
    float wvv[8];
    wvv[0] = e0.x * (svt + sv0.x); wvv[1] = e0.y * (svt + sv0.y);
    wvv[2] = e0.z * (svt + sv0.z); wvv[3] = e0.w * (svt + sv0.w);
    wvv[4] = e1.x * (svt + sv1.x); wvv[5] = e1.y * (svt + sv1.y);
    wvv[6] = e1.z * (svt + sv1.z); wvv[7] = e1.w * (svt + sv1.w);
    bf16x8 ah, al;
    #pragma unroll
    for (int q = 0; q < 8; ++q) {
      bf16_t h = (bf16_t)wvv[q];
      ah[q] = h;
      al[q] = (bf16_t)(wvv[q] - (float)h);
    }

    __syncthreads();                 // previous chunk's LDS reads done
    {
      uint* rh0 = (uint*)XTh[sc4 + 0]; uint* rh1 = (uint*)XTh[sc4 + 1];
      uint* rh2 = (uint*)XTh[sc4 + 2]; uint* rh3 = (uint*)XTh[sc4 + 3];
      rh0[sp] = (uint)H0.x | ((uint)H1.x << 16);
      rh1[sp] = (uint)H0.y | ((uint)H1.y << 16);
      rh2[sp] = (uint)H0.z | ((uint)H1.z << 16);
      rh3[sp] = (uint)H0.w | ((uint)H1.w << 16);
      uint* rl0 = (uint*)XTl[sc4 + 0]; uint* rl1 = (uint*)XTl[sc4 + 1];
      uint* rl2 = (uint*)XTl[sc4 + 2]; uint* rl3 = (uint*)XTl[sc4 + 3];
      rl0[sp] = (uint)L0.x | ((uint)L1.x << 16);
      rl1[sp] = (uint)L0.y | ((uint)L1.y << 16);
      rl2[sp] = (uint)L0.z | ((uint)L1.z << 16);
      rl3[sp] = (uint)L0.w | ((uint)L1.w << 16);
    }
    __syncthreads();

    #pragma unroll
    for (int jt = 0; jt < 4; ++jt) {
      bf16x8 bh = *(const bf16x8*)&XTh[jt * 16 + l15][quad * 8];
      bf16x8 bl = *(const bf16x8*)&XTl[jt * 16 + l15][quad * 8];
      acc[jt] = __builtin_amdgcn_mfma_f32_16x16x32_bf16(ah, bh, acc[jt], 0, 0, 0);
      acc[jt] = __builtin_amdgcn_mfma_f32_16x16x32_bf16(al, bh, acc[jt], 0, 0, 0);
      acc[jt] = __builtin_amdgcn_mfma_f32_16x16x32_bf16(ah, bl, acc[jt], 0, 0, 0);
    }
  }

  const float coef = 0.5f * cst[lam_idx] * (1.0f / (2.0f * Tn));
  const float ss = cst[ss_idx];
  #pragma unroll
  for (int jt = 0; jt < 4; ++jt) {
    const int col = c0 + jt * 16 + l15;
    #pragma unroll
    for (int r = 0; r < 4; ++r) {
      const int row = t0 + wv * 16 + quad * 4 + r;
      const size_t off = ((size_t)b * Tn + row) * Cn + col;
      dst[off] = src[off] * ss + coef * acc[jt][r];
    }
  }
}

// dst = s1 + 0.5*cst[lam_idx]*s2/z[row]
__global__ void __launch_bounds__(256) velupd_kernel(
    const float* s1, const float* s2, const float* __restrict__ zb,
    float* dst, const float* __restrict__ cst, int lam_idx) {
  const int blk = blockIdx.x;
  const int row = blk / 3;
  const size_t i = (size_t)row * Cn + (blk % 3) * 256 + threadIdx.x;
  const float vs = 0.5f * cst[lam_idx];
  dst[i] = s1[i] + vs * s2[i] / zb[row];
}

__global__ void __launch_bounds__(256) rot_kernel(
    float* X, float* Pi, float* bX, float* bPi, float c, float sn) {
  const size_t i = (size_t)blockIdx.x * 256 + threadIdx.x;
  const float x = X[i], p = Pi[i], bx = bX[i], bp = bPi[i];
  const float dX = x - bx, dPi = p - bp, sX = x + bx, sPi = p + bp;
  X[i]   = 0.5f * (sX + c * dX + sn * dPi);
  Pi[i]  = 0.5f * (sPi - sn * dX + c * dPi);
  bX[i]  = 0.5f * (sX - c * dX - sn * dPi);
  bPi[i] = 0.5f * (sPi + sn * dX - c * dPi);
}

// Final LayerNorm (fp32 out, in-place capable)
__global__ void __launch_bounds__(256) ln_f32_kernel(
    const float* src, const float* __restrict__ w,
    float* dst, const float* __restrict__ cst, int alpha_idx) {
  const int row = blockIdx.x;
  const int tid = threadIdx.x;
  const float alpha = cst[alpha_idx];
  const float* x = src + (size_t)row * Cn;
  float v0 = alpha * x[tid];
  float v1 = alpha * x[tid + 256];
  float v2 = alpha * x[tid + 512];
  __shared__ float red[256];
  red[tid] = v0 + v1 + v2;
  __syncthreads();
  for (int off = 128; off > 0; off >>= 1) {
    if (tid < off) red[tid] += red[tid + off];
    __syncthreads();
  }
  const float m = red[0] * (1.0f / Cn);
  __syncthreads();
  const float d0 = v0 - m, d1 = v1 - m, d2 = v2 - m;
  red[tid] = d0 * d0 + d1 * d1 + d2 * d2;
  __syncthreads();
  for (int off = 128; off > 0; off >>= 1) {
    if (tid < off) red[tid] += red[tid + off];
    __syncthreads();
  }
  const float rstd = rsqrtf(red[0] * (1.0f / Cn) + LNEPS);
  float* y = dst + (size_t)row * Cn;
  y[tid]       = d0 * rstd * w[tid];
  y[tid + 256] = d1 * rstd * w[tid + 256];
  y[tid + 512] = d2 * rstd * w[tid + 512];
}

extern "C" void kernel_launch(void* const* d_in, const int* in_sizes, int n_in,
                              void* d_out, int out_size, void* d_ws, size_t ws_size,
                              hipStream_t stream) {
  (void)in_sizes; (void)n_in; (void)out_size;
  const float* Xk  = (const float*)d_in[0];
  const float* Pk  = (const float*)d_in[1];
  const float* lw  = (const float*)d_in[2];
  const float* lvw = (const float*)d_in[3];
  const int*   kp  = (const int*)d_in[4];

  float* Xo = (float*)d_out;        // X state in d_out[0:BTC]
  float* Po = Xo + NBTC;            // Pi state in d_out[BTC:2BTC]

  char* wp = (char*)d_ws;
  float*  bX  = (float*)wp;  wp += NBTC * sizeof(float);
  float*  bPi = (float*)wp;  wp += NBTC * sizeof(float);
  bf16_t* XnH = (bf16_t*)wp; wp += NBTC * sizeof(bf16_t);
  bf16_t* XnL = (bf16_t*)wp; wp += NBTC * sizeof(bf16_t);
  float*  E   = (float*)wp;  wp += (size_t)Bn * Tn * Tn * sizeof(float);
  float*  zb  = (float*)wp;  wp += (size_t)Bn * Tn * sizeof(float);
  float*  sv  = (float*)wp;  wp += (size_t)Bn * Tn * sizeof(float);
  float*  cst = (float*)wp;  wp += 256;
  const size_t need = (size_t)(wp - (char*)d_ws);
  if (ws_size < need) {
    fprintf(stderr, "[kernel] ws too small: %zu < %zu\n", ws_size, need);
    return;
  }

  const dim3 b256(256);
  const dim3 gLN(Bn * Tn);
  const dim3 gZ(528, Bn);                 // flat triangular tiles x batch
  const dim3 gCore(Cn / 64, Tn / 64, Bn);
  const dim3 gEW(Bn * Tn * 3);
  const float rc = (float)cos(2.0), rs = (float)sin(2.0);   // theta = 2*XI*h

  prep_consts<<<1, 1, 0, stream>>>(kp, cst);

  // ---- Stage A: X-side = Xk, p = Pk (lam*Lam = 1) ----
  ln_hl_kernel<<<gLN, b256, 0, stream>>>(Xk, lw, XnH, XnL, zb, cst, 6);
  zpass_mfma<<<gZ, b256, 0, stream>>>(XnH, XnL, E, zb);
  sv_kernel<<<gLN, b256, 0, stream>>>(Pk, zb, sv, cst, 6);
  corepass_mfma<<<gCore, b256, 0, stream>>>(E, XnH, XnL, sv, Pk, Po, cst, 0, 0);
  velupd_kernel<<<gEW, b256, 0, stream>>>(Xk, Pk, zb, bX, cst, 6);

  // ---- Stage B: X-side = bX, Pi-side = Po ----
  ln_hl_kernel<<<gLN, b256, 0, stream>>>(bX, lw, XnH, XnL, zb, cst, 6);
  zpass_mfma<<<gZ, b256, 0, stream>>>(XnH, XnL, E, zb);
  sv_kernel<<<gLN, b256, 0, stream>>>(Po, zb, sv, cst, 3);
  velupd_kernel<<<gEW, b256, 0, stream>>>(Xk, Po, zb, Xo, cst, 3);
  corepass_mfma<<<gCore, b256, 0, stream>>>(E, XnH, XnL, sv, Pk, bPi, cst, 0, 2);

  // ---- rotation mixing ----
  rot_kernel<<<gEW, b256, 0, stream>>>(Xo, Po, bX, bPi, rc, rs);

  // ---- Stage C: X-side = bX, Pi-side = Po ----
  ln_hl_kernel<<<gLN, b256, 0, stream>>>(bX, lw, XnH, XnL, zb, cst, 6);
  zpass_mfma<<<gZ, b256, 0, stream>>>(XnH, XnL, E, zb);
  sv_kernel<<<gLN, b256, 0, stream>>>(Po, zb, sv, cst, 3);
  velupd_kernel<<<gEW, b256, 0, stream>>>(Xo, Po, zb, Xo, cst, 3);
  corepass_mfma<<<gCore, b256, 0, stream>>>(E, XnH, XnL, sv, bPi, bPi, cst, 6, 2);

  // ---- Stage D: X-side = Xo, p = lam_tk1*bPi ----
  ln_hl_kernel<<<gLN, b256, 0, stream>>>(Xo, lw, XnH, XnL, zb, cst, 6);
  zpass_mfma<<<gZ, b256, 0, stream>>>(XnH, XnL, E, zb);
  sv_kernel<<<gLN, b256, 0, stream>>>(bPi, zb, sv, cst, 5);
  corepass_mfma<<<gCore, b256, 0, stream>>>(E, XnH, XnL, sv, Po, Po, cst, 6, 4);

  // ---- Final: Pk1 = LN(lam_tk1 * Pi) * ln_v_w (in place on Po) ----
  ln_f32_kernel<<<gLN, b256, 0, stream>>>(Po, lvw, Po, cst, 5);
}

// Round 3
// 1446.244 us; speedup vs baseline: 2.5354x; 1.1763x over previous
//
#include <hip/hip_runtime.h>
#include <hip/hip_bf16.h>
#include <cstdio>
#include <cmath>

// Problem constants (B,T,C,NH fixed by the reference)
constexpr int   Bn = 4;
constexpr int   Tn = 2048;
constexpr int   Cn = 768;
constexpr float COEF  = 0.125f / 12.0f;   // SCALE / NH
constexpr float EPSZ  = 1e-8f;
constexpr float LNEPS = 1e-5f;
#define NBTC ((size_t)Bn * Tn * Cn)

typedef __bf16 bf16_t;
typedef bf16_t bf16x8 __attribute__((ext_vector_type(8)));
typedef float  f32x4  __attribute__((ext_vector_type(4)));

// async global->LDS, 16B per lane. LDS dest is wave-uniform base + lane*16.
__device__ __forceinline__ void gload16(const void* g, void* l) {
  __builtin_amdgcn_global_load_lds(
      (const __attribute__((address_space(1))) unsigned int*)g,
      (__attribute__((address_space(3))) unsigned int*)l,
      16, 0, 0);
}

// cst[] indices: 0 Lam_tk, 1 lam_tk, 2 Lam_tbar, 3 lam_tbar, 4 Lam_tk1, 5 lam_tk1, 6 = 1.0
__global__ void prep_consts(const int* kp, float* cst) {
  if (threadIdx.x == 0 && blockIdx.x == 0) {
    float tk = 1.0f + (float)(*kp);
    float tb = tk + 0.5f;
    float t1 = tk + 1.0f;
    cst[0] = tk * tk * tk; cst[1] = 1.0f / cst[0];
    cst[2] = tb * tb * tb; cst[3] = 1.0f / cst[2];
    cst[4] = t1 * t1 * t1; cst[5] = 1.0f / cst[4];
    cst[6] = 1.0f;
  }
}

// LayerNorm of (alpha*src) with weight w -> hi/lo bf16 split outputs.
// Also zeroes zbuf[row] for the stage's upcoming zpass atomics.
__global__ void __launch_bounds__(256) ln_hl_kernel(
    const float* __restrict__ src, const float* __restrict__ w,
    bf16_t* __restrict__ outH, bf16_t* __restrict__ outL,
    float* __restrict__ zbuf, const float* __restrict__ cst, int alpha_idx) {
  const int row = blockIdx.x;
  const int tid = threadIdx.x;
  const float alpha = cst[alpha_idx];
  const float* x = src + (size_t)row * Cn;
  float v0 = alpha * x[tid];
  float v1 = alpha * x[tid + 256];
  float v2 = alpha * x[tid + 512];
  __shared__ float red[256];
  red[tid] = v0 + v1 + v2;
  __syncthreads();
  for (int off = 128; off > 0; off >>= 1) {
    if (tid < off) red[tid] += red[tid + off];
    __syncthreads();
  }
  const float m = red[0] * (1.0f / Cn);
  __syncthreads();
  const float d0 = v0 - m, d1 = v1 - m, d2 = v2 - m;
  red[tid] = d0 * d0 + d1 * d1 + d2 * d2;
  __syncthreads();
  for (int off = 128; off > 0; off >>= 1) {
    if (tid < off) red[tid] += red[tid + off];
    __syncthreads();
  }
  const float rstd = rsqrtf(red[0] * (1.0f / Cn) + LNEPS);
  const size_t base = (size_t)row * Cn;
  float f0 = d0 * rstd * w[tid];
  float f1 = d1 * rstd * w[tid + 256];
  float f2 = d2 * rstd * w[tid + 512];
  bf16_t h0 = (bf16_t)f0, h1 = (bf16_t)f1, h2 = (bf16_t)f2;
  outH[base + tid]       = h0;  outL[base + tid]       = (bf16_t)(f0 - (float)h0);
  outH[base + tid + 256] = h1;  outL[base + tid + 256] = (bf16_t)(f1 - (float)h1);
  outH[base + tid + 512] = h2;  outL[base + tid + 512] = (bf16_t)(f2 - (float)h2);
  if (tid == 0) zbuf[row] = 0.0f;
}

// Causal gram, 128x128 tile, m97-style: global_load_lds staging of A/B hi+lo
// 32-k chunks, ds_read_b128 fragments, split-bf16 MFMA (3 products).
// E = exp(clip(S*COEF)) masked-causal, stored fp32; row sums -> atomicAdd zbuf.
// grid = (136 triangular 128-tiles, Bn), block = 256.
__global__ void __launch_bounds__(256) zpass_mfma(
    const bf16_t* __restrict__ XnH, const bf16_t* __restrict__ XnL,
    float* __restrict__ E, float* __restrict__ zbuf) {
  const int b = blockIdx.y;
  int l = blockIdx.x;
  int it = (int)((sqrtf(8.0f * (float)l + 1.0f) - 1.0f) * 0.5f);
  while ((it + 1) * (it + 2) / 2 <= l) ++it;
  while (it * (it + 1) / 2 > l) --it;
  const int st = l - it * (it + 1) / 2;
  const int t0 = it * 128, s0 = st * 128;

  const int tid  = threadIdx.x;
  const int lane = tid & 63;
  const int wv   = tid >> 6;
  const int wr   = wv >> 1, wc = wv & 1;   // 2x2 wave quadrants (64x64 each)
  const int quad = lane >> 4, l15 = lane & 15;

  const bf16_t* XbH = XnH + (size_t)b * Tn * Cn;
  const bf16_t* XbL = XnL + (size_t)b * Tn * Cn;
  float* Eb = E + (size_t)b * Tn * Tn;

  __shared__ bf16_t Ah[128 * 32], Al[128 * 32], Bh[128 * 32], Bl[128 * 32];

  // staging: wave wv, instr j covers tile-rows [wv*16 + j*64, +16)
  // lane i -> row base+ (i>>2), elems (i&3)*8 (16B)
  const int srow = lane >> 2;
  const int scol = (lane & 3) * 8;

  f32x4 acc[4][4] = {};

  for (int c0 = 0; c0 < Cn; c0 += 32) {
    __syncthreads();                 // protect LDS while prev chunk still read
    #pragma unroll
    for (int j = 0; j < 2; ++j) {
      const int rb = wv * 16 + j * 64;          // slab row base (wave-uniform)
      const size_t ga = (size_t)(t0 + rb + srow) * Cn + c0 + scol;
      const size_t gb = (size_t)(s0 + rb + srow) * Cn + c0 + scol;
      gload16(XbH + ga, Ah + rb * 32);
      gload16(XbL + ga, Al + rb * 32);
      gload16(XbH + gb, Bh + rb * 32);
      gload16(XbL + gb, Bl + rb * 32);
    }
    __syncthreads();                 // drain vmcnt + all slabs present

    bf16x8 ah[4], al[4], bh[4], bl[4];
    #pragma unroll
    for (int i = 0; i < 4; ++i) {
      ah[i] = *(const bf16x8*)&Ah[(wr * 64 + i * 16 + l15) * 32 + quad * 8];
      al[i] = *(const bf16x8*)&Al[(wr * 64 + i * 16 + l15) * 32 + quad * 8];
      bh[i] = *(const bf16x8*)&Bh[(wc * 64 + i * 16 + l15) * 32 + quad * 8];
      bl[i] = *(const bf16x8*)&Bl[(wc * 64 + i * 16 + l15) * 32 + quad * 8];
    }
    #pragma unroll
    for (int i = 0; i < 4; ++i)
      #pragma unroll
      for (int j = 0; j < 4; ++j) {
        acc[i][j] = __builtin_amdgcn_mfma_f32_16x16x32_bf16(ah[i], bh[j], acc[i][j], 0, 0, 0);
        acc[i][j] = __builtin_amdgcn_mfma_f32_16x16x32_bf16(al[i], bh[j], acc[i][j], 0, 0, 0);
        acc[i][j] = __builtin_amdgcn_mfma_f32_16x16x32_bf16(ah[i], bl[j], acc[i][j], 0, 0, 0);
      }
  }

  float zacc[4][4];
  #pragma unroll
  for (int i = 0; i < 4; ++i)
    #pragma unroll
    for (int r = 0; r < 4; ++r) zacc[i][r] = 0.0f;

  #pragma unroll
  for (int i = 0; i < 4; ++i) {
    #pragma unroll
    for (int j = 0; j < 4; ++j) {
      const int col = s0 + wc * 64 + j * 16 + l15;
      #pragma unroll
      for (int r = 0; r < 4; ++r) {
        const int row = t0 + wr * 64 + i * 16 + quad * 4 + r;
        float sV = acc[i][j][r] * COEF;
        sV = fminf(fmaxf(sV, -60.f), 60.f);
        const float e = (col <= row) ? __expf(sV) : 0.f;
        Eb[(size_t)row * Tn + col] = e;
        zacc[i][r] += e;
      }
    }
  }
  #pragma unroll
  for (int i = 0; i < 4; ++i)
    #pragma unroll
    for (int r = 0; r < 4; ++r) {
      float v = zacc[i][r];
      v += __shfl_xor(v, 1);
      v += __shfl_xor(v, 2);
      v += __shfl_xor(v, 4);
      v += __shfl_xor(v, 8);
      if (l15 == 0)
        atomicAdd(&zbuf[b * Tn + t0 + wr * 64 + i * 16 + quad * 4 + r], v);
    }
}

// Finalize z (raw sum -> max(sum/T, EPS)) and compute sv = |p|^2 / (z^2 + EPS).
__global__ void __launch_bounds__(256) sv_kernel(
    const float* __restrict__ Pisrc, float* __restrict__ zbuf,
    float* __restrict__ sv, const float* __restrict__ cst, int ps_idx) {
  const int row = blockIdx.x;
  const int tid = threadIdx.x;
  const float* p = Pisrc + (size_t)row * Cn;
  const float v0 = p[tid], v1 = p[tid + 256], v2 = p[tid + 512];
  __shared__ float red[256];
  red[tid] = v0 * v0 + v1 * v1 + v2 * v2;
  __syncthreads();
  for (int off = 128; off > 0; off >>= 1) {
    if (tid < off) red[tid] += red[tid + off];
    __syncthreads();
  }
  if (tid == 0) {
    const float ps = cst[ps_idx];
    const float a = red[0] * ps * ps;
    const float zf = fmaxf(zbuf[row] * (1.0f / Tn), EPSZ);
    zbuf[row] = zf;
    sv[row] = a / (zf * zf + EPSZ);
  }
}

// core GEMM, 128x128 tile: dst = src*cst[ss_idx] + (tau*Lam/(2T)) * W @ Xn,
// W[t][s] = E[t][s]*(sv[t]+sv[s]-2) built in-register as bf16 hi/lo (A operand).
// Xn^T chunk (128c x 32s, hi/lo) pair-packed into LDS (B operand).
// grid = (Cn/128, Tn/128, Bn); heavy-K blocks launched first. src/dst may alias.
__global__ void __launch_bounds__(256) corepass_mfma(
    const float* __restrict__ E,
    const bf16_t* __restrict__ XnH, const bf16_t* __restrict__ XnL,
    const float* __restrict__ sv, const float* src, float* dst,
    const float* __restrict__ cst, int ss_idx, int lam_idx) {
  const int b  = blockIdx.z;
  const int it = (int)gridDim.y - 1 - (int)blockIdx.y;   // big K first
  const int ic = blockIdx.x;
  const int t0 = it * 128, c0 = ic * 128;

  const int tid  = threadIdx.x;
  const int lane = tid & 63;
  const int wv   = tid >> 6;
  const int wr   = wv >> 1, wc = wv & 1;
  const int quad = lane >> 4, l15 = lane & 15;

  const float*  Eb  = E + (size_t)b * Tn * Tn;
  const ushort* XbH = (const ushort*)(XnH + (size_t)b * Tn * Cn);
  const ushort* XbL = (const ushort*)(XnL + (size_t)b * Tn * Cn);
  const float*  svB = sv + b * Tn;

  __shared__ ushort XTh[128 * 32];   // [c][s], 64B rows
  __shared__ ushort XTl[128 * 32];

  const float* eRow[4];
  float svt[4];
  #pragma unroll
  for (int i = 0; i < 4; ++i) {
    const int rg = t0 + wr * 64 + i * 16 + l15;
    eRow[i] = Eb + (size_t)rg * Tn;
    svt[i]  = svB[rg] - 2.0f;
  }

  // staging map: thread covers c = cg*4..+3, s = sq*4..+3 of the 32-s chunk
  const int cg = tid & 31;
  const int sq = tid >> 5;

  union U4 { ushort4 v; ushort u[4]; };

  f32x4 acc[4][4] = {};
  const int chunks = (it + 1) * 4;
  for (int kc = 0; kc < chunks; ++kc) {
    const int ss0 = kc * 32;

    // global staging loads (registers), issued before barriers
    U4 hx[4], lx[4];
    const ushort* hp = XbH + (size_t)(ss0 + sq * 4) * Cn + c0 + cg * 4;
    const ushort* lp = XbL + (size_t)(ss0 + sq * 4) * Cn + c0 + cg * 4;
    #pragma unroll
    for (int u = 0; u < 4; ++u) {
      hx[u].v = *(const ushort4*)(hp + (size_t)u * Cn);
      lx[u].v = *(const ushort4*)(lp + (size_t)u * Cn);
    }

    // A operand: W hi/lo per t-tile (overlaps with staging latency)
    bf16x8 wh[4], wl[4];
    {
      const float4 sva = *(const float4*)(svB + ss0 + quad * 8);
      const float4 svb = *(const float4*)(svB + ss0 + quad * 8 + 4);
      const float fs[8] = {sva.x, sva.y, sva.z, sva.w, svb.x, svb.y, svb.z, svb.w};
      #pragma unroll
      for (int i = 0; i < 4; ++i) {
        const float4 e0 = *(const float4*)(eRow[i] + ss0 + quad * 8);
        const float4 e1 = *(const float4*)(eRow[i] + ss0 + quad * 8 + 4);
        const float ev[8] = {e0.x, e0.y, e0.z, e0.w, e1.x, e1.y, e1.z, e1.w};
        #pragma unroll
        for (int q = 0; q < 8; ++q) {
          const float w = ev[q] * (svt[i] + fs[q]);
          const bf16_t h = (bf16_t)w;
          wh[i][q] = h;
          wl[i][q] = (bf16_t)(w - (float)h);
        }
      }
    }

    __syncthreads();                 // prev chunk's LDS reads done
    #pragma unroll
    for (int v = 0; v < 4; ++v) {
      const int cl = cg * 4 + v;
      uint2 ph, pl;
      ph.x = (uint)hx[0].u[v] | ((uint)hx[1].u[v] << 16);
      ph.y = (uint)hx[2].u[v] | ((uint)hx[3].u[v] << 16);
      pl.x = (uint)lx[0].u[v] | ((uint)lx[1].u[v] << 16);
      pl.y = (uint)lx[2].u[v] | ((uint)lx[3].u[v] << 16);
      *(uint2*)&XTh[cl * 32 + sq * 4] = ph;
      *(uint2*)&XTl[cl * 32 + sq * 4] = pl;
    }
    __syncthreads();

    #pragma unroll
    for (int j = 0; j < 4; ++j) {
      const bf16x8 bh = *(const bf16x8*)&XTh[(wc * 64 + j * 16 + l15) * 32 + quad * 8];
      const bf16x8 bl = *(const bf16x8*)&XTl[(wc * 64 + j * 16 + l15) * 32 + quad * 8];
      #pragma unroll
      for (int i = 0; i < 4; ++i) {
        acc[i][j] = __builtin_amdgcn_mfma_f32_16x16x32_bf16(wh[i], bh, acc[i][j], 0, 0, 0);
        acc[i][j] = __builtin_amdgcn_mfma_f32_16x16x32_bf16(wl[i], bh, acc[i][j], 0, 0, 0);
        acc[i][j] = __builtin_amdgcn_mfma_f32_16x16x32_bf16(wh[i], bl, acc[i][j], 0, 0, 0);
      }
    }
  }

  const float coef = 0.5f * cst[lam_idx] * (1.0f / (2.0f * Tn));
  const float ss = cst[ss_idx];
  #pragma unroll
  for (int i = 0; i < 4; ++i) {
    #pragma unroll
    for (int j = 0; j < 4; ++j) {
      const int col = c0 + wc * 64 + j * 16 + l15;
      #pragma unroll
      for (int r = 0; r < 4; ++r) {
        const int row = t0 + wr * 64 + i * 16 + quad * 4 + r;
        const size_t off = ((size_t)b * Tn + row) * Cn + col;
        dst[off] = src[off] * ss + coef * acc[i][j][r];
      }
    }
  }
}

// dst = s1 + 0.5*cst[lam_idx]*s2/z[row]
__global__ void __launch_bounds__(256) velupd_kernel(
    const float* s1, const float* s2, const float* __restrict__ zb,
    float* dst, const float* __restrict__ cst, int lam_idx) {
  const int blk = blockIdx.x;
  const int row = blk / 3;
  const size_t i = (size_t)row * Cn + (blk % 3) * 256 + threadIdx.x;
  const float vs = 0.5f * cst[lam_idx];
  dst[i] = s1[i] + vs * s2[i] / zb[row];
}

__global__ void __launch_bounds__(256) rot_kernel(
    float* X, float* Pi, float* bX, float* bPi, float c, float sn) {
  const size_t i = (size_t)blockIdx.x * 256 + threadIdx.x;
  const float x = X[i], p = Pi[i], bx = bX[i], bp = bPi[i];
  const float dX = x - bx, dPi = p - bp, sX = x + bx, sPi = p + bp;
  X[i]   = 0.5f * (sX + c * dX + sn * dPi);
  Pi[i]  = 0.5f * (sPi - sn * dX + c * dPi);
  bX[i]  = 0.5f * (sX - c * dX - sn * dPi);
  bPi[i] = 0.5f * (sPi + sn * dX - c * dPi);
}

// Final LayerNorm (fp32 out, in-place capable)
__global__ void __launch_bounds__(256) ln_f32_kernel(
    const float* src, const float* __restrict__ w,
    float* dst, const float* __restrict__ cst, int alpha_idx) {
  const int row = blockIdx.x;
  const int tid = threadIdx.x;
  const float alpha = cst[alpha_idx];
  const float* x = src + (size_t)row * Cn;
  float v0 = alpha * x[tid];
  float v1 = alpha * x[tid + 256];
  float v2 = alpha * x[tid + 512];
  __shared__ float red[256];
  red[tid] = v0 + v1 + v2;
  __syncthreads();
  for (int off = 128; off > 0; off >>= 1) {
    if (tid < off) red[tid] += red[tid + off];
    __syncthreads();
  }
  const float m = red[0] * (1.0f / Cn);
  __syncthreads();
  const float d0 = v0 - m, d1 = v1 - m, d2 = v2 - m;
  red[tid] = d0 * d0 + d1 * d1 + d2 * d2;
  __syncthreads();
  for (int off = 128; off > 0; off >>= 1) {
    if (tid < off) red[tid] += red[tid + off];
    __syncthreads();
  }
  const float rstd = rsqrtf(red[0] * (1.0f / Cn) + LNEPS);
  float* y = dst + (size_t)row * Cn;
  y[tid]       = d0 * rstd * w[tid];
  y[tid + 256] = d1 * rstd * w[tid + 256];
  y[tid + 512] = d2 * rstd * w[tid + 512];
}

extern "C" void kernel_launch(void* const* d_in, const int* in_sizes, int n_in,
                              void* d_out, int out_size, void* d_ws, size_t ws_size,
                              hipStream_t stream) {
  (void)in_sizes; (void)n_in; (void)out_size;
  const float* Xk  = (const float*)d_in[0];
  const float* Pk  = (const float*)d_in[1];
  const float* lw  = (const float*)d_in[2];
  const float* lvw = (const float*)d_in[3];
  const int*   kp  = (const int*)d_in[4];

  float* Xo = (float*)d_out;        // X state in d_out[0:BTC]
  float* Po = Xo + NBTC;            // Pi state in d_out[BTC:2BTC]

  char* wp = (char*)d_ws;
  float*  bX  = (float*)wp;  wp += NBTC * sizeof(float);
  float*  bPi = (float*)wp;  wp += NBTC * sizeof(float);
  bf16_t* XnH = (bf16_t*)wp; wp += NBTC * sizeof(bf16_t);
  bf16_t* XnL = (bf16_t*)wp; wp += NBTC * sizeof(bf16_t);
  float*  E   = (float*)wp;  wp += (size_t)Bn * Tn * Tn * sizeof(float);
  float*  zb  = (float*)wp;  wp += (size_t)Bn * Tn * sizeof(float);
  float*  sv  = (float*)wp;  wp += (size_t)Bn * Tn * sizeof(float);
  float*  cst = (float*)wp;  wp += 256;
  const size_t need = (size_t)(wp - (char*)d_ws);
  if (ws_size < need) {
    fprintf(stderr, "[kernel] ws too small: %zu < %zu\n", ws_size, need);
    return;
  }

  const dim3 b256(256);
  const dim3 gLN(Bn * Tn);
  const dim3 gZ(136, Bn);                    // triangular 128-tiles x batch
  const dim3 gCore(Cn / 128, Tn / 128, Bn);  // (6,16,4)
  const dim3 gEW(Bn * Tn * 3);
  const float rc = (float)cos(2.0), rs = (float)sin(2.0);   // theta = 2*XI*h

  prep_consts<<<1, 1, 0, stream>>>(kp, cst);

  // ---- Stage A: X-side = Xk, p = Pk (lam*Lam = 1) ----
  ln_hl_kernel<<<gLN, b256, 0, stream>>>(Xk, lw, XnH, XnL, zb, cst, 6);
  zpass_mfma<<<gZ, b256, 0, stream>>>(XnH, XnL, E, zb);
  sv_kernel<<<gLN, b256, 0, stream>>>(Pk, zb, sv, cst, 6);
  corepass_mfma<<<gCore, b256, 0, stream>>>(E, XnH, XnL, sv, Pk, Po, cst, 0, 0);
  velupd_kernel<<<gEW, b256, 0, stream>>>(Xk, Pk, zb, bX, cst, 6);

  // ---- Stage B: X-side = bX, Pi-side = Po ----
  ln_hl_kernel<<<gLN, b256, 0, stream>>>(bX, lw, XnH, XnL, zb, cst, 6);
  zpass_mfma<<<gZ, b256, 0, stream>>>(XnH, XnL, E, zb);
  sv_kernel<<<gLN, b256, 0, stream>>>(Po, zb, sv, cst, 3);
  velupd_kernel<<<gEW, b256, 0, stream>>>(Xk, Po, zb, Xo, cst, 3);
  corepass_mfma<<<gCore, b256, 0, stream>>>(E, XnH, XnL, sv, Pk, bPi, cst, 0, 2);

  // ---- rotation mixing ----
  rot_kernel<<<gEW, b256, 0, stream>>>(Xo, Po, bX, bPi, rc, rs);

  // ---- Stage C: X-side = bX, Pi-side = Po ----
  ln_hl_kernel<<<gLN, b256, 0, stream>>>(bX, lw, XnH, XnL, zb, cst, 6);
  zpass_mfma<<<gZ, b256, 0, stream>>>(XnH, XnL, E, zb);
  sv_kernel<<<gLN, b256, 0, stream>>>(Po, zb, sv, cst, 3);
  velupd_kernel<<<gEW, b256, 0, stream>>>(Xo, Po, zb, Xo, cst, 3);
  corepass_mfma<<<gCore, b256, 0, stream>>>(E, XnH, XnL, sv, bPi, bPi, cst, 6, 2);

  // ---- Stage D: X-side = Xo, p = lam_tk1*bPi ----
  ln_hl_kernel<<<gLN, b256, 0, stream>>>(Xo, lw, XnH, XnL, zb, cst, 6);
  zpass_mfma<<<gZ, b256, 0, stream>>>(XnH, XnL, E, zb);
  sv_kernel<<<gLN, b256, 0, stream>>>(bPi, zb, sv, cst, 5);
  corepass_mfma<<<gCore, b256, 0, stream>>>(E, XnH, XnL, sv, Po, Po, cst, 6, 4);

  // ---- Final: Pk1 = LN(lam_tk1 * Pi) * ln_v_w (in place on Po) ----
  ln_f32_kernel<<<gLN, b256, 0, stream>>>(Po, lvw, Po, cst, 5);
}

// Round 4
// 1097.390 us; speedup vs baseline: 3.3414x; 1.3179x over previous
//
#include <hip/hip_runtime.h>
#include <hip/hip_bf16.h>
#include <cstdio>
#include <cmath>

// Problem constants (B,T,C,NH fixed by the reference)
constexpr int   Bn = 4;
constexpr int   Tn = 2048;
constexpr int   Cn = 768;
constexpr float COEF  = 0.125f / 12.0f;   // SCALE / NH
constexpr float EPSZ  = 1e-8f;
constexpr float LNEPS = 1e-5f;
constexpr int   NTRI  = 136;              // triangular 128-tiles per batch
#define NBTC ((size_t)Bn * Tn * Cn)

typedef __bf16 bf16_t;
typedef bf16_t bf16x8 __attribute__((ext_vector_type(8)));
typedef float  f32x4  __attribute__((ext_vector_type(4)));
typedef ushort u16x8  __attribute__((ext_vector_type(8)));

// async global->LDS, 16B per lane. LDS dest is wave-uniform base + lane*16.
__device__ __forceinline__ void gload16(const void* g, void* l) {
  __builtin_amdgcn_global_load_lds(
      (const __attribute__((address_space(1))) unsigned int*)g,
      (__attribute__((address_space(3))) unsigned int*)l,
      16, 0, 0);
}

__device__ __forceinline__ ushort bf16_bits(float f) {
  bf16_t h = (bf16_t)f;
  return __builtin_bit_cast(ushort, h);
}
__device__ __forceinline__ float bits_to_f(ushort u) {
  return (float)__builtin_bit_cast(bf16_t, u);
}

// cst[] indices: 0 Lam_tk, 1 lam_tk, 2 Lam_tbar, 3 lam_tbar, 4 Lam_tk1, 5 lam_tk1, 6 = 1.0
__global__ void prep_consts(const int* kp, float* cst) {
  if (threadIdx.x == 0 && blockIdx.x == 0) {
    float tk = 1.0f + (float)(*kp);
    float tb = tk + 0.5f;
    float t1 = tk + 1.0f;
    cst[0] = tk * tk * tk; cst[1] = 1.0f / cst[0];
    cst[2] = tb * tb * tb; cst[3] = 1.0f / cst[2];
    cst[4] = t1 * t1 * t1; cst[5] = 1.0f / cst[4];
    cst[6] = 1.0f;
  }
}

// LayerNorm of (alpha*src) with weight w -> hi/lo bf16 split outputs.
// Also zeroes zbuf[row] for the stage's upcoming zpass atomics.
__global__ void __launch_bounds__(256) ln_hl_kernel(
    const float* __restrict__ src, const float* __restrict__ w,
    bf16_t* __restrict__ outH, bf16_t* __restrict__ outL,
    float* __restrict__ zbuf, const float* __restrict__ cst, int alpha_idx) {
  const int row = blockIdx.x;
  const int tid = threadIdx.x;
  const float alpha = cst[alpha_idx];
  const float* x = src + (size_t)row * Cn;
  float v0 = alpha * x[tid];
  float v1 = alpha * x[tid + 256];
  float v2 = alpha * x[tid + 512];
  __shared__ float red[256];
  red[tid] = v0 + v1 + v2;
  __syncthreads();
  for (int off = 128; off > 0; off >>= 1) {
    if (tid < off) red[tid] += red[tid + off];
    __syncthreads();
  }
  const float m = red[0] * (1.0f / Cn);
  __syncthreads();
  const float d0 = v0 - m, d1 = v1 - m, d2 = v2 - m;
  red[tid] = d0 * d0 + d1 * d1 + d2 * d2;
  __syncthreads();
  for (int off = 128; off > 0; off >>= 1) {
    if (tid < off) red[tid] += red[tid + off];
    __syncthreads();
  }
  const float rstd = rsqrtf(red[0] * (1.0f / Cn) + LNEPS);
  const size_t base = (size_t)row * Cn;
  float f0 = d0 * rstd * w[tid];
  float f1 = d1 * rstd * w[tid + 256];
  float f2 = d2 * rstd * w[tid + 512];
  bf16_t h0 = (bf16_t)f0, h1 = (bf16_t)f1, h2 = (bf16_t)f2;
  outH[base + tid]       = h0;  outL[base + tid]       = (bf16_t)(f0 - (float)h0);
  outH[base + tid + 256] = h1;  outL[base + tid + 256] = (bf16_t)(f1 - (float)h1);
  outH[base + tid + 512] = h2;  outL[base + tid + 512] = (bf16_t)(f2 - (float)h2);
  if (tid == 0) zbuf[row] = 0.0f;
}

// Causal gram, 128x128 tile, m97-style. E = exp(clip(S*COEF)) stored as
// bf16 hi/lo in PACKED triangular-tile layout [b][tri][128][128].
// Row sums (fp32) -> atomicAdd zbuf. grid = (136, Bn), block 256.
__global__ void __launch_bounds__(256) zpass_mfma(
    const bf16_t* __restrict__ XnH, const bf16_t* __restrict__ XnL,
    ushort* __restrict__ Ehp, ushort* __restrict__ Elp,
    float* __restrict__ zbuf) {
  const int b = blockIdx.y;
  int l = blockIdx.x;
  int it = (int)((sqrtf(8.0f * (float)l + 1.0f) - 1.0f) * 0.5f);
  while ((it + 1) * (it + 2) / 2 <= l) ++it;
  while (it * (it + 1) / 2 > l) --it;
  const int st = l - it * (it + 1) / 2;
  const int t0 = it * 128, s0 = st * 128;
  const int tri = it * (it + 1) / 2 + st;

  const int tid  = threadIdx.x;
  const int lane = tid & 63;
  const int wv   = tid >> 6;
  const int wr   = wv >> 1, wc = wv & 1;   // 2x2 wave quadrants (64x64 each)
  const int quad = lane >> 4, l15 = lane & 15;

  const bf16_t* XbH = XnH + (size_t)b * Tn * Cn;
  const bf16_t* XbL = XnL + (size_t)b * Tn * Cn;
  ushort* EhT = Ehp + ((size_t)b * NTRI + tri) * 16384;
  ushort* ElT = Elp + ((size_t)b * NTRI + tri) * 16384;

  __shared__ bf16_t Ah[128 * 32], Al[128 * 32], Bh[128 * 32], Bl[128 * 32];

  const int srow = lane >> 2;
  const int scol = (lane & 3) * 8;

  f32x4 acc[4][4] = {};

  for (int c0 = 0; c0 < Cn; c0 += 32) {
    __syncthreads();                 // protect LDS while prev chunk still read
    #pragma unroll
    for (int j = 0; j < 2; ++j) {
      const int rb = wv * 16 + j * 64;          // slab row base (wave-uniform)
      const size_t ga = (size_t)(t0 + rb + srow) * Cn + c0 + scol;
      const size_t gb = (size_t)(s0 + rb + srow) * Cn + c0 + scol;
      gload16(XbH + ga, Ah + rb * 32);
      gload16(XbL + ga, Al + rb * 32);
      gload16(XbH + gb, Bh + rb * 32);
      gload16(XbL + gb, Bl + rb * 32);
    }
    __syncthreads();                 // drain vmcnt + all slabs present

    bf16x8 ah[4], al[4], bh[4], bl[4];
    #pragma unroll
    for (int i = 0; i < 4; ++i) {
      ah[i] = *(const bf16x8*)&Ah[(wr * 64 + i * 16 + l15) * 32 + quad * 8];
      al[i] = *(const bf16x8*)&Al[(wr * 64 + i * 16 + l15) * 32 + quad * 8];
      bh[i] = *(const bf16x8*)&Bh[(wc * 64 + i * 16 + l15) * 32 + quad * 8];
      bl[i] = *(const bf16x8*)&Bl[(wc * 64 + i * 16 + l15) * 32 + quad * 8];
    }
    #pragma unroll
    for (int i = 0; i < 4; ++i)
      #pragma unroll
      for (int j = 0; j < 4; ++j) {
        acc[i][j] = __builtin_amdgcn_mfma_f32_16x16x32_bf16(ah[i], bh[j], acc[i][j], 0, 0, 0);
        acc[i][j] = __builtin_amdgcn_mfma_f32_16x16x32_bf16(al[i], bh[j], acc[i][j], 0, 0, 0);
        acc[i][j] = __builtin_amdgcn_mfma_f32_16x16x32_bf16(ah[i], bl[j], acc[i][j], 0, 0, 0);
      }
  }

  float zacc[4][4];
  #pragma unroll
  for (int i = 0; i < 4; ++i)
    #pragma unroll
    for (int r = 0; r < 4; ++r) zacc[i][r] = 0.0f;

  #pragma unroll
  for (int i = 0; i < 4; ++i) {
    #pragma unroll
    for (int j = 0; j < 4; ++j) {
      const int colL = wc * 64 + j * 16 + l15;
      #pragma unroll
      for (int r = 0; r < 4; ++r) {
        const int rowL = wr * 64 + i * 16 + quad * 4 + r;
        float sV = acc[i][j][r] * COEF;
        sV = fminf(fmaxf(sV, -60.f), 60.f);
        const float e = (s0 + colL <= t0 + rowL) ? __expf(sV) : 0.f;
        const bf16_t h = (bf16_t)e;
        EhT[rowL * 128 + colL] = __builtin_bit_cast(ushort, h);
        ElT[rowL * 128 + colL] = bf16_bits(e - (float)h);
        zacc[i][r] += e;
      }
    }
  }
  #pragma unroll
  for (int i = 0; i < 4; ++i)
    #pragma unroll
    for (int r = 0; r < 4; ++r) {
      float v = zacc[i][r];
      v += __shfl_xor(v, 1);
      v += __shfl_xor(v, 2);
      v += __shfl_xor(v, 4);
      v += __shfl_xor(v, 8);
      if (l15 == 0)
        atomicAdd(&zbuf[b * Tn + t0 + wr * 64 + i * 16 + quad * 4 + r], v);
    }
}

// Finalize z (raw sum -> max(sum/T, EPS)) and compute sv = |p|^2 / (z^2 + EPS).
__global__ void __launch_bounds__(256) sv_kernel(
    const float* __restrict__ Pisrc, float* __restrict__ zbuf,
    float* __restrict__ sv, const float* __restrict__ cst, int ps_idx) {
  const int row = blockIdx.x;
  const int tid = threadIdx.x;
  const float* p = Pisrc + (size_t)row * Cn;
  const float v0 = p[tid], v1 = p[tid + 256], v2 = p[tid + 512];
  __shared__ float red[256];
  red[tid] = v0 * v0 + v1 * v1 + v2 * v2;
  __syncthreads();
  for (int off = 128; off > 0; off >>= 1) {
    if (tid < off) red[tid] += red[tid + off];
    __syncthreads();
  }
  if (tid == 0) {
    const float ps = cst[ps_idx];
    const float a = red[0] * ps * ps;
    const float zf = fmaxf(zbuf[row] * (1.0f / Tn), EPSZ);
    zbuf[row] = zf;
    sv[row] = a / (zf * zf + EPSZ);
  }
}

// In-place W-build: E[t,s] *= (sv[t] + sv[s] - 2), on the packed hi/lo tiles.
// grid = (16 s-tiles, 16 t-tiles, Bn); skip strictly-upper tiles.
__global__ void __launch_bounds__(256) wbuild_kernel(
    ushort* __restrict__ Ehp, ushort* __restrict__ Elp,
    const float* __restrict__ sv) {
  const int st = blockIdx.x, it = blockIdx.y, b = blockIdx.z;
  if (st > it) return;
  const int tri = it * (it + 1) / 2 + st;
  ushort* EhT = Ehp + ((size_t)b * NTRI + tri) * 16384;
  ushort* ElT = Elp + ((size_t)b * NTRI + tri) * 16384;
  const float* svB = sv + b * Tn;

  const int tid = threadIdx.x;
  const int r  = tid >> 1;            // 0..127
  const int ch = (tid & 1) * 64;      // col half
  const float svt2 = svB[it * 128 + r] - 2.0f;
  const int base = r * 128 + ch;
  #pragma unroll
  for (int v = 0; v < 8; ++v) {
    u16x8 h8 = *(const u16x8*)&EhT[base + v * 8];
    u16x8 l8 = *(const u16x8*)&ElT[base + v * 8];
    const float4 sa = *(const float4*)(svB + st * 128 + ch + v * 8);
    const float4 sb = *(const float4*)(svB + st * 128 + ch + v * 8 + 4);
    const float ss[8] = {sa.x, sa.y, sa.z, sa.w, sb.x, sb.y, sb.z, sb.w};
    u16x8 nh, nl;
    #pragma unroll
    for (int q = 0; q < 8; ++q) {
      const float e = bits_to_f(h8[q]) + bits_to_f(l8[q]);
      const float w = e * (svt2 + ss[q]);
      const bf16_t hh = (bf16_t)w;
      nh[q] = __builtin_bit_cast(ushort, hh);
      nl[q] = bf16_bits(w - (float)hh);
    }
    *(u16x8*)&EhT[base + v * 8] = nh;
    *(u16x8*)&ElT[base + v * 8] = nl;
  }
}

// core GEMM, pure m97 shape: dst = src*cst[ss_idx] + coef * W @ Xn.
// A = packed W tiles (gload16), B = Xn^T chunk staged via padded LDS transpose.
// Tile 128t x 64c; grid = (12, 16, Bn), big-K first. src/dst may alias.
__global__ void __launch_bounds__(256) corepass_mfma(
    const ushort* __restrict__ Whp, const ushort* __restrict__ Wlp,
    const bf16_t* __restrict__ XnH, const bf16_t* __restrict__ XnL,
    const float* src, float* dst,
    const float* __restrict__ cst, int ss_idx, int lam_idx) {
  const int b  = blockIdx.z;
  const int it = (int)gridDim.y - 1 - (int)blockIdx.y;   // big K first
  const int ic = blockIdx.x;
  const int t0 = it * 128, c0 = ic * 64;

  const int tid  = threadIdx.x;
  const int lane = tid & 63;
  const int wv   = tid >> 6;
  const int wr   = wv >> 1, wc = wv & 1;   // wave covers 64t x 32c
  const int quad = lane >> 4, l15 = lane & 15;

  const ushort* WhB = Whp + (size_t)b * NTRI * 16384;
  const ushort* WlB = Wlp + (size_t)b * NTRI * 16384;
  const ushort* XbH = (const ushort*)(XnH + (size_t)b * Tn * Cn);
  const ushort* XbL = (const ushort*)(XnL + (size_t)b * Tn * Cn);

  __shared__ ushort Ah[128 * 32], Al[128 * 32];   // W slabs  (8 KB each)
  __shared__ ushort Bh[64 * 40],  Bl[64 * 40];    // X^T slabs, stride 40

  const int srow = lane >> 2;
  const int scol = (lane & 3) * 8;
  const int triBase = it * (it + 1) / 2;

  // B staging: thread covers c = cg*4..+3, s = sq*2, sq*2+1
  const int cg = tid & 15;
  const int sq = tid >> 4;

  union U4 { ushort4 v; ushort u[4]; };

  f32x4 acc[4][2] = {};
  const int chunks = (it + 1) * 4;
  for (int kc = 0; kc < chunks; ++kc) {
    const int ss0 = kc * 32;
    const int stile = ss0 >> 7, soff = ss0 & 127;
    const ushort* tileH = WhB + (size_t)(triBase + stile) * 16384 + soff;
    const ushort* tileL = WlB + (size_t)(triBase + stile) * 16384 + soff;

    // B global loads into registers (issued before barriers)
    U4 H0, H1, L0, L1;
    {
      const ushort* hp = XbH + (size_t)(ss0 + sq * 2) * Cn + c0 + cg * 4;
      const ushort* lp = XbL + (size_t)(ss0 + sq * 2) * Cn + c0 + cg * 4;
      H0.v = *(const ushort4*)hp;
      H1.v = *(const ushort4*)(hp + Cn);
      L0.v = *(const ushort4*)lp;
      L1.v = *(const ushort4*)(lp + Cn);
    }

    __syncthreads();                 // prev chunk's LDS reads done
    // A slabs: async global->LDS
    #pragma unroll
    for (int j = 0; j < 2; ++j) {
      const int rb = wv * 16 + j * 64;
      gload16(tileH + (size_t)(rb + srow) * 128 + scol, Ah + rb * 32);
      gload16(tileL + (size_t)(rb + srow) * 128 + scol, Al + rb * 32);
    }
    // B transpose-stage (padded stride 40 -> 2-way max conflicts)
    #pragma unroll
    for (int v = 0; v < 4; ++v) {
      const int cl = cg * 4 + v;
      ((uint*)Bh)[cl * 20 + sq] = (uint)H0.u[v] | ((uint)H1.u[v] << 16);
      ((uint*)Bl)[cl * 20 + sq] = (uint)L0.u[v] | ((uint)L1.u[v] << 16);
    }
    __syncthreads();                 // drain vmcnt + LDS writes visible

    bf16x8 ah[4], al[4], bh[2], bl[2];
    #pragma unroll
    for (int i = 0; i < 4; ++i) {
      ah[i] = *(const bf16x8*)&Ah[(wr * 64 + i * 16 + l15) * 32 + quad * 8];
      al[i] = *(const bf16x8*)&Al[(wr * 64 + i * 16 + l15) * 32 + quad * 8];
    }
    #pragma unroll
    for (int j = 0; j < 2; ++j) {
      bh[j] = *(const bf16x8*)&Bh[(wc * 32 + j * 16 + l15) * 40 + quad * 8];
      bl[j] = *(const bf16x8*)&Bl[(wc * 32 + j * 16 + l15) * 40 + quad * 8];
    }
    #pragma unroll
    for (int i = 0; i < 4; ++i)
      #pragma unroll
      for (int j = 0; j < 2; ++j) {
        acc[i][j] = __builtin_amdgcn_mfma_f32_16x16x32_bf16(ah[i], bh[j], acc[i][j], 0, 0, 0);
        acc[i][j] = __builtin_amdgcn_mfma_f32_16x16x32_bf16(al[i], bh[j], acc[i][j], 0, 0, 0);
        acc[i][j] = __builtin_amdgcn_mfma_f32_16x16x32_bf16(ah[i], bl[j], acc[i][j], 0, 0, 0);
      }
  }

  const float coef = 0.5f * cst[lam_idx] * (1.0f / (2.0f * Tn));
  const float ss = cst[ss_idx];
  #pragma unroll
  for (int i = 0; i < 4; ++i) {
    #pragma unroll
    for (int j = 0; j < 2; ++j) {
      const int col = c0 + wc * 32 + j * 16 + l15;
      #pragma unroll
      for (int r = 0; r < 4; ++r) {
        const int row = t0 + wr * 64 + i * 16 + quad * 4 + r;
        const size_t off = ((size_t)b * Tn + row) * Cn + col;
        dst[off] = src[off] * ss + coef * acc[i][j][r];
      }
    }
  }
}

// dst = s1 + 0.5*cst[lam_idx]*s2/z[row]
__global__ void __launch_bounds__(256) velupd_kernel(
    const float* s1, const float* s2, const float* __restrict__ zb,
    float* dst, const float* __restrict__ cst, int lam_idx) {
  const int blk = blockIdx.x;
  const int row = blk / 3;
  const size_t i = (size_t)row * Cn + (blk % 3) * 256 + threadIdx.x;
  const float vs = 0.5f * cst[lam_idx];
  dst[i] = s1[i] + vs * s2[i] / zb[row];
}

__global__ void __launch_bounds__(256) rot_kernel(
    float* X, float* Pi, float* bX, float* bPi, float c, float sn) {
  const size_t i = (size_t)blockIdx.x * 256 + threadIdx.x;
  const float x = X[i], p = Pi[i], bx = bX[i], bp = bPi[i];
  const float dX = x - bx, dPi = p - bp, sX = x + bx, sPi = p + bp;
  X[i]   = 0.5f * (sX + c * dX + sn * dPi);
  Pi[i]  = 0.5f * (sPi - sn * dX + c * dPi);
  bX[i]  = 0.5f * (sX - c * dX - sn * dPi);
  bPi[i] = 0.5f * (sPi + sn * dX - c * dPi);
}

// Final LayerNorm (fp32 out, in-place capable)
__global__ void __launch_bounds__(256) ln_f32_kernel(
    const float* src, const float* __restrict__ w,
    float* dst, const float* __restrict__ cst, int alpha_idx) {
  const int row = blockIdx.x;
  const int tid = threadIdx.x;
  const float alpha = cst[alpha_idx];
  const float* x = src + (size_t)row * Cn;
  float v0 = alpha * x[tid];
  float v1 = alpha * x[tid + 256];
  float v2 = alpha * x[tid + 512];
  __shared__ float red[256];
  red[tid] = v0 + v1 + v2;
  __syncthreads();
  for (int off = 128; off > 0; off >>= 1) {
    if (tid < off) red[tid] += red[tid + off];
    __syncthreads();
  }
  const float m = red[0] * (1.0f / Cn);
  __syncthreads();
  const float d0 = v0 - m, d1 = v1 - m, d2 = v2 - m;
  red[tid] = d0 * d0 + d1 * d1 + d2 * d2;
  __syncthreads();
  for (int off = 128; off > 0; off >>= 1) {
    if (tid < off) red[tid] += red[tid + off];
    __syncthreads();
  }
  const float rstd = rsqrtf(red[0] * (1.0f / Cn) + LNEPS);
  float* y = dst + (size_t)row * Cn;
  y[tid]       = d0 * rstd * w[tid];
  y[tid + 256] = d1 * rstd * w[tid + 256];
  y[tid + 512] = d2 * rstd * w[tid + 512];
}

extern "C" void kernel_launch(void* const* d_in, const int* in_sizes, int n_in,
                              void* d_out, int out_size, void* d_ws, size_t ws_size,
                              hipStream_t stream) {
  (void)in_sizes; (void)n_in; (void)out_size;
  const float* Xk  = (const float*)d_in[0];
  const float* Pk  = (const float*)d_in[1];
  const float* lw  = (const float*)d_in[2];
  const float* lvw = (const float*)d_in[3];
  const int*   kp  = (const int*)d_in[4];

  float* Xo = (float*)d_out;        // X state in d_out[0:BTC]
  float* Po = Xo + NBTC;            // Pi state in d_out[BTC:2BTC]

  char* wp = (char*)d_ws;
  float*  bX  = (float*)wp;  wp += NBTC * sizeof(float);
  float*  bPi = (float*)wp;  wp += NBTC * sizeof(float);
  bf16_t* XnH = (bf16_t*)wp; wp += NBTC * sizeof(bf16_t);
  bf16_t* XnL = (bf16_t*)wp; wp += NBTC * sizeof(bf16_t);
  ushort* Ehp = (ushort*)wp; wp += (size_t)Bn * NTRI * 16384 * sizeof(ushort);
  ushort* Elp = (ushort*)wp; wp += (size_t)Bn * NTRI * 16384 * sizeof(ushort);
  float*  zb  = (float*)wp;  wp += (size_t)Bn * Tn * sizeof(float);
  float*  sv  = (float*)wp;  wp += (size_t)Bn * Tn * sizeof(float);
  float*  cst = (float*)wp;  wp += 256;
  const size_t need = (size_t)(wp - (char*)d_ws);
  if (ws_size < need) {
    fprintf(stderr, "[kernel] ws too small: %zu < %zu\n", ws_size, need);
    return;
  }

  const dim3 b256(256);
  const dim3 gLN(Bn * Tn);
  const dim3 gZ(NTRI, Bn);                   // triangular 128-tiles x batch
  const dim3 gW(16, 16, Bn);                 // wbuild (skips upper)
  const dim3 gCore(Cn / 64, Tn / 128, Bn);   // (12,16,4) = 768 blocks
  const dim3 gEW(Bn * Tn * 3);
  const float rc = (float)cos(2.0), rs = (float)sin(2.0);   // theta = 2*XI*h

  prep_consts<<<1, 1, 0, stream>>>(kp, cst);

  // ---- Stage A: X-side = Xk, p = Pk (lam*Lam = 1) ----
  ln_hl_kernel<<<gLN, b256, 0, stream>>>(Xk, lw, XnH, XnL, zb, cst, 6);
  zpass_mfma<<<gZ, b256, 0, stream>>>(XnH, XnL, Ehp, Elp, zb);
  sv_kernel<<<gLN, b256, 0, stream>>>(Pk, zb, sv, cst, 6);
  wbuild_kernel<<<gW, b256, 0, stream>>>(Ehp, Elp, sv);
  corepass_mfma<<<gCore, b256, 0, stream>>>(Ehp, Elp, XnH, XnL, Pk, Po, cst, 0, 0);
  velupd_kernel<<<gEW, b256, 0, stream>>>(Xk, Pk, zb, bX, cst, 6);

  // ---- Stage B: X-side = bX, Pi-side = Po ----
  ln_hl_kernel<<<gLN, b256, 0, stream>>>(bX, lw, XnH, XnL, zb, cst, 6);
  zpass_mfma<<<gZ, b256, 0, stream>>>(XnH, XnL, Ehp, Elp, zb);
  sv_kernel<<<gLN, b256, 0, stream>>>(Po, zb, sv, cst, 3);
  wbuild_kernel<<<gW, b256, 0, stream>>>(Ehp, Elp, sv);
  velupd_kernel<<<gEW, b256, 0, stream>>>(Xk, Po, zb, Xo, cst, 3);
  corepass_mfma<<<gCore, b256, 0, stream>>>(Ehp, Elp, XnH, XnL, Pk, bPi, cst, 0, 2);

  // ---- rotation mixing ----
  rot_kernel<<<gEW, b256, 0, stream>>>(Xo, Po, bX, bPi, rc, rs);

  // ---- Stage C: X-side = bX, Pi-side = Po ----
  ln_hl_kernel<<<gLN, b256, 0, stream>>>(bX, lw, XnH, XnL, zb, cst, 6);
  zpass_mfma<<<gZ, b256, 0, stream>>>(XnH, XnL, Ehp, Elp, zb);
  sv_kernel<<<gLN, b256, 0, stream>>>(Po, zb, sv, cst, 3);
  wbuild_kernel<<<gW, b256, 0, stream>>>(Ehp, Elp, sv);
  velupd_kernel<<<gEW, b256, 0, stream>>>(Xo, Po, zb, Xo, cst, 3);
  corepass_mfma<<<gCore, b256, 0, stream>>>(Ehp, Elp, XnH, XnL, bPi, bPi, cst, 6, 2);

  // ---- Stage D: X-side = Xo, p = lam_tk1*bPi ----
  ln_hl_kernel<<<gLN, b256, 0, stream>>>(Xo, lw, XnH, XnL, zb, cst, 6);
  zpass_mfma<<<gZ, b256, 0, stream>>>(XnH, XnL, Ehp, Elp, zb);
  sv_kernel<<<gLN, b256, 0, stream>>>(bPi, zb, sv, cst, 5);
  wbuild_kernel<<<gW, b256, 0, stream>>>(Ehp, Elp, sv);
  corepass_mfma<<<gCore, b256, 0, stream>>>(Ehp, Elp, XnH, XnL, Po, Po, cst, 6, 4);

  // ---- Final: Pk1 = LN(lam_tk1 * Pi) * ln_v_w (in place on Po) ----
  ln_f32_kernel<<<gLN, b256, 0, stream>>>(Po, lvw, Po, cst, 5);
}

// Round 5
// 842.637 us; speedup vs baseline: 4.3516x; 1.3023x over previous
//
#include <hip/hip_runtime.h>
#include <hip/hip_bf16.h>
#include <cstdio>
#include <cmath>

// Problem constants (B,T,C,NH fixed by the reference)
constexpr int   Bn = 4;
constexpr int   Tn = 2048;
constexpr int   Cn = 768;
constexpr float COEF  = 0.125f / 12.0f;   // SCALE / NH
constexpr float EPSZ  = 1e-8f;
constexpr float LNEPS = 1e-5f;
constexpr int   NTRI  = 136;              // triangular 128-tiles per batch
#define NBTC ((size_t)Bn * Tn * Cn)

typedef __bf16 bf16_t;
typedef bf16_t bf16x8 __attribute__((ext_vector_type(8)));
typedef float  f32x4  __attribute__((ext_vector_type(4)));
typedef ushort u16x8  __attribute__((ext_vector_type(8)));

// async global->LDS, 16B per lane. LDS dest is wave-uniform base + lane*16.
__device__ __forceinline__ void gload16(const void* g, void* l) {
  __builtin_amdgcn_global_load_lds(
      (const __attribute__((address_space(1))) unsigned int*)g,
      (__attribute__((address_space(3))) unsigned int*)l,
      16, 0, 0);
}

__device__ __forceinline__ ushort bf16_bits(float f) {
  bf16_t h = (bf16_t)f;
  return __builtin_bit_cast(ushort, h);
}
__device__ __forceinline__ float bits_to_f(ushort u) {
  return (float)__builtin_bit_cast(bf16_t, u);
}

// cst[] indices: 0 Lam_tk, 1 lam_tk, 2 Lam_tbar, 3 lam_tbar, 4 Lam_tk1, 5 lam_tk1, 6 = 1.0
__global__ void prep_consts(const int* kp, float* cst) {
  if (threadIdx.x == 0 && blockIdx.x == 0) {
    float tk = 1.0f + (float)(*kp);
    float tb = tk + 0.5f;
    float t1 = tk + 1.0f;
    cst[0] = tk * tk * tk; cst[1] = 1.0f / cst[0];
    cst[2] = tb * tb * tb; cst[3] = 1.0f / cst[2];
    cst[4] = t1 * t1 * t1; cst[5] = 1.0f / cst[4];
    cst[6] = 1.0f;
  }
}

// LayerNorm of (alpha*src) with weight w -> hi/lo bf16 split outputs.
// Also zeroes zbuf[row] for the stage's upcoming zpass atomics.
__global__ void __launch_bounds__(256) ln_hl_kernel(
    const float* __restrict__ src, const float* __restrict__ w,
    bf16_t* __restrict__ outH, bf16_t* __restrict__ outL,
    float* __restrict__ zbuf, const float* __restrict__ cst, int alpha_idx) {
  const int row = blockIdx.x;
  const int tid = threadIdx.x;
  const float alpha = cst[alpha_idx];
  const float* x = src + (size_t)row * Cn;
  float v0 = alpha * x[tid];
  float v1 = alpha * x[tid + 256];
  float v2 = alpha * x[tid + 512];
  __shared__ float red[256];
  red[tid] = v0 + v1 + v2;
  __syncthreads();
  for (int off = 128; off > 0; off >>= 1) {
    if (tid < off) red[tid] += red[tid + off];
    __syncthreads();
  }
  const float m = red[0] * (1.0f / Cn);
  __syncthreads();
  const float d0 = v0 - m, d1 = v1 - m, d2 = v2 - m;
  red[tid] = d0 * d0 + d1 * d1 + d2 * d2;
  __syncthreads();
  for (int off = 128; off > 0; off >>= 1) {
    if (tid < off) red[tid] += red[tid + off];
    __syncthreads();
  }
  const float rstd = rsqrtf(red[0] * (1.0f / Cn) + LNEPS);
  const size_t base = (size_t)row * Cn;
  float f0 = d0 * rstd * w[tid];
  float f1 = d1 * rstd * w[tid + 256];
  float f2 = d2 * rstd * w[tid + 512];
  bf16_t h0 = (bf16_t)f0, h1 = (bf16_t)f1, h2 = (bf16_t)f2;
  outH[base + tid]       = h0;  outL[base + tid]       = (bf16_t)(f0 - (float)h0);
  outH[base + tid + 256] = h1;  outL[base + tid + 256] = (bf16_t)(f1 - (float)h1);
  outH[base + tid + 512] = h2;  outL[base + tid + 512] = (bf16_t)(f2 - (float)h2);
  if (tid == 0) zbuf[row] = 0.0f;
}

// Transpose XnH [b][s][c] -> XT [b][c][s] (bf16). grid (Tn/64, Cn/64, Bn).
__global__ void __launch_bounds__(256) xt_kernel(
    const ushort* __restrict__ Xh, ushort* __restrict__ XT) {
  const int b = blockIdx.z;
  const int s0 = blockIdx.x * 64, c0 = blockIdx.y * 64;
  const int tid = threadIdx.x;
  __shared__ ushort t[64][68];      // stride 68 ushorts = 136B (8B-aligned rows)
  const ushort* src = Xh + (size_t)b * Tn * Cn;
  ushort* dst = XT + (size_t)b * Cn * Tn;
  #pragma unroll
  for (int p = 0; p < 4; ++p) {
    const int r = p * 16 + (tid >> 4);
    const int c = (tid & 15) * 4;
    const ushort4 v = *(const ushort4*)&src[(size_t)(s0 + r) * Cn + c0 + c];
    *(ushort4*)&t[r][c] = v;
  }
  __syncthreads();
  #pragma unroll
  for (int p = 0; p < 4; ++p) {
    const int cc = p * 16 + (tid >> 4);
    const int ss = (tid & 15) * 4;
    ushort4 o;
    o.x = t[ss + 0][cc]; o.y = t[ss + 1][cc];
    o.z = t[ss + 2][cc]; o.w = t[ss + 3][cc];
    *(ushort4*)&dst[(size_t)(c0 + cc) * Tn + s0 + ss] = o;
  }
}

// Causal gram, 128x128 tile, m97-style. E = exp(clip(S*COEF)) stored as
// SINGLE bf16 in PACKED triangular-tile layout [b][tri][128][128].
// Row sums (fp32) -> atomicAdd zbuf. grid = (136, Bn), block 256.
__global__ void __launch_bounds__(256) zpass_mfma(
    const bf16_t* __restrict__ XnH, const bf16_t* __restrict__ XnL,
    ushort* __restrict__ Ehp, float* __restrict__ zbuf) {
  const int b = blockIdx.y;
  int l = blockIdx.x;
  int it = (int)((sqrtf(8.0f * (float)l + 1.0f) - 1.0f) * 0.5f);
  while ((it + 1) * (it + 2) / 2 <= l) ++it;
  while (it * (it + 1) / 2 > l) --it;
  const int st = l - it * (it + 1) / 2;
  const int t0 = it * 128, s0 = st * 128;
  const int tri = it * (it + 1) / 2 + st;

  const int tid  = threadIdx.x;
  const int lane = tid & 63;
  const int wv   = tid >> 6;
  const int wr   = wv >> 1, wc = wv & 1;   // 2x2 wave quadrants (64x64 each)
  const int quad = lane >> 4, l15 = lane & 15;

  const bf16_t* XbH = XnH + (size_t)b * Tn * Cn;
  const bf16_t* XbL = XnL + (size_t)b * Tn * Cn;
  ushort* EhT = Ehp + ((size_t)b * NTRI + tri) * 16384;

  __shared__ bf16_t Ah[128 * 32], Al[128 * 32], Bh[128 * 32], Bl[128 * 32];

  const int srow = lane >> 2;
  const int scol = (lane & 3) * 8;

  f32x4 acc[4][4] = {};

  for (int c0 = 0; c0 < Cn; c0 += 32) {
    __syncthreads();                 // protect LDS while prev chunk still read
    #pragma unroll
    for (int j = 0; j < 2; ++j) {
      const int rb = wv * 16 + j * 64;          // slab row base (wave-uniform)
      const size_t ga = (size_t)(t0 + rb + srow) * Cn + c0 + scol;
      const size_t gb = (size_t)(s0 + rb + srow) * Cn + c0 + scol;
      gload16(XbH + ga, Ah + rb * 32);
      gload16(XbL + ga, Al + rb * 32);
      gload16(XbH + gb, Bh + rb * 32);
      gload16(XbL + gb, Bl + rb * 32);
    }
    __syncthreads();                 // drain vmcnt + all slabs present

    bf16x8 ah[4], al[4], bh[4], bl[4];
    #pragma unroll
    for (int i = 0; i < 4; ++i) {
      ah[i] = *(const bf16x8*)&Ah[(wr * 64 + i * 16 + l15) * 32 + quad * 8];
      al[i] = *(const bf16x8*)&Al[(wr * 64 + i * 16 + l15) * 32 + quad * 8];
      bh[i] = *(const bf16x8*)&Bh[(wc * 64 + i * 16 + l15) * 32 + quad * 8];
      bl[i] = *(const bf16x8*)&Bl[(wc * 64 + i * 16 + l15) * 32 + quad * 8];
    }
    #pragma unroll
    for (int i = 0; i < 4; ++i)
      #pragma unroll
      for (int j = 0; j < 4; ++j) {
        acc[i][j] = __builtin_amdgcn_mfma_f32_16x16x32_bf16(ah[i], bh[j], acc[i][j], 0, 0, 0);
        acc[i][j] = __builtin_amdgcn_mfma_f32_16x16x32_bf16(al[i], bh[j], acc[i][j], 0, 0, 0);
        acc[i][j] = __builtin_amdgcn_mfma_f32_16x16x32_bf16(ah[i], bl[j], acc[i][j], 0, 0, 0);
      }
  }

  float zacc[4][4];
  #pragma unroll
  for (int i = 0; i < 4; ++i)
    #pragma unroll
    for (int r = 0; r < 4; ++r) zacc[i][r] = 0.0f;

  #pragma unroll
  for (int i = 0; i < 4; ++i) {
    #pragma unroll
    for (int j = 0; j < 4; ++j) {
      const int colL = wc * 64 + j * 16 + l15;
      #pragma unroll
      for (int r = 0; r < 4; ++r) {
        const int rowL = wr * 64 + i * 16 + quad * 4 + r;
        float sV = acc[i][j][r] * COEF;
        sV = fminf(fmaxf(sV, -60.f), 60.f);
        const float e = (s0 + colL <= t0 + rowL) ? __expf(sV) : 0.f;
        EhT[rowL * 128 + colL] = bf16_bits(e);
        zacc[i][r] += e;
      }
    }
  }
  #pragma unroll
  for (int i = 0; i < 4; ++i)
    #pragma unroll
    for (int r = 0; r < 4; ++r) {
      float v = zacc[i][r];
      v += __shfl_xor(v, 1);
      v += __shfl_xor(v, 2);
      v += __shfl_xor(v, 4);
      v += __shfl_xor(v, 8);
      if (l15 == 0)
        atomicAdd(&zbuf[b * Tn + t0 + wr * 64 + i * 16 + quad * 4 + r], v);
    }
}

// Finalize z (raw sum -> max(sum/T, EPS)) and compute sv = |p|^2 / (z^2 + EPS).
__global__ void __launch_bounds__(256) sv_kernel(
    const float* __restrict__ Pisrc, float* __restrict__ zbuf,
    float* __restrict__ sv, const float* __restrict__ cst, int ps_idx) {
  const int row = blockIdx.x;
  const int tid = threadIdx.x;
  const float* p = Pisrc + (size_t)row * Cn;
  const float v0 = p[tid], v1 = p[tid + 256], v2 = p[tid + 512];
  __shared__ float red[256];
  red[tid] = v0 * v0 + v1 * v1 + v2 * v2;
  __syncthreads();
  for (int off = 128; off > 0; off >>= 1) {
    if (tid < off) red[tid] += red[tid + off];
    __syncthreads();
  }
  if (tid == 0) {
    const float ps = cst[ps_idx];
    const float a = red[0] * ps * ps;
    const float zf = fmaxf(zbuf[row] * (1.0f / Tn), EPSZ);
    zbuf[row] = zf;
    sv[row] = a / (zf * zf + EPSZ);
  }
}

// In-place W-build: E[t,s] *= (sv[t] + sv[s] - 2), packed single-bf16 tiles.
// grid = (16 s-tiles, 16 t-tiles, Bn); skip strictly-upper tiles.
__global__ void __launch_bounds__(256) wbuild_kernel(
    ushort* __restrict__ Ehp, const float* __restrict__ sv) {
  const int st = blockIdx.x, it = blockIdx.y, b = blockIdx.z;
  if (st > it) return;
  const int tri = it * (it + 1) / 2 + st;
  ushort* EhT = Ehp + ((size_t)b * NTRI + tri) * 16384;
  const float* svB = sv + b * Tn;

  const int tid = threadIdx.x;
  const int r  = tid >> 1;            // 0..127
  const int ch = (tid & 1) * 64;      // col half
  const float svt2 = svB[it * 128 + r] - 2.0f;
  const int base = r * 128 + ch;
  #pragma unroll
  for (int v = 0; v < 8; ++v) {
    u16x8 h8 = *(const u16x8*)&EhT[base + v * 8];
    const float4 sa = *(const float4*)(svB + st * 128 + ch + v * 8);
    const float4 sb = *(const float4*)(svB + st * 128 + ch + v * 8 + 4);
    const float ss[8] = {sa.x, sa.y, sa.z, sa.w, sb.x, sb.y, sb.z, sb.w};
    u16x8 nh;
    #pragma unroll
    for (int q = 0; q < 8; ++q) {
      const float w = bits_to_f(h8[q]) * (svt2 + ss[q]);
      nh[q] = bf16_bits(w);
    }
    *(u16x8*)&EhT[base + v * 8] = nh;
  }
}

// core GEMM, plain bf16: dst = src*cst[ss_idx] + coef * W @ Xn.
// A = packed W tiles (gload16), B = pre-transposed XT [b][c][s] (gload16).
// Tile 128t x 64c; grid = (12, 16, Bn), big-K first. src/dst may alias.
__global__ void __launch_bounds__(256) corepass_mfma(
    const ushort* __restrict__ Whp, const ushort* __restrict__ XT,
    const float* src, float* dst,
    const float* __restrict__ cst, int ss_idx, int lam_idx) {
  const int b  = blockIdx.z;
  const int it = (int)gridDim.y - 1 - (int)blockIdx.y;   // big K first
  const int ic = blockIdx.x;
  const int t0 = it * 128, c0 = ic * 64;

  const int tid  = threadIdx.x;
  const int lane = tid & 63;
  const int wv   = tid >> 6;
  const int wr   = wv >> 1, wc = wv & 1;   // wave covers 64t x 32c
  const int quad = lane >> 4, l15 = lane & 15;

  const ushort* WhB = Whp + (size_t)b * NTRI * 16384;
  const ushort* XTb = XT + (size_t)b * Cn * Tn;

  __shared__ ushort Ah[128 * 32];   // W slab  (8 KB)
  __shared__ ushort Bh[64 * 32];    // X^T slab (4 KB)

  const int srow = lane >> 2;
  const int scol = (lane & 3) * 8;
  const int triBase = it * (it + 1) / 2;

  f32x4 acc[4][2] = {};
  const int chunks = (it + 1) * 4;
  for (int kc = 0; kc < chunks; ++kc) {
    const int ss0 = kc * 32;
    const int stile = kc >> 2, soff = (kc & 3) * 32;
    const ushort* tileH = WhB + (size_t)(triBase + stile) * 16384 + soff;

    __syncthreads();                 // prev chunk's LDS reads done
    #pragma unroll
    for (int j = 0; j < 2; ++j) {
      const int rb = wv * 16 + j * 64;
      gload16(tileH + (size_t)(rb + srow) * 128 + scol, Ah + rb * 32);
    }
    gload16(XTb + (size_t)(c0 + wv * 16 + srow) * Tn + ss0 + scol,
            Bh + wv * 16 * 32);
    __syncthreads();                 // drain vmcnt

    bf16x8 ah[4], bh[2];
    #pragma unroll
    for (int i = 0; i < 4; ++i)
      ah[i] = *(const bf16x8*)&Ah[(wr * 64 + i * 16 + l15) * 32 + quad * 8];
    #pragma unroll
    for (int j = 0; j < 2; ++j)
      bh[j] = *(const bf16x8*)&Bh[(wc * 32 + j * 16 + l15) * 32 + quad * 8];
    #pragma unroll
    for (int i = 0; i < 4; ++i)
      #pragma unroll
      for (int j = 0; j < 2; ++j)
        acc[i][j] = __builtin_amdgcn_mfma_f32_16x16x32_bf16(ah[i], bh[j], acc[i][j], 0, 0, 0);
  }

  const float coef = 0.5f * cst[lam_idx] * (1.0f / (2.0f * Tn));
  const float ss = cst[ss_idx];
  #pragma unroll
  for (int i = 0; i < 4; ++i) {
    #pragma unroll
    for (int j = 0; j < 2; ++j) {
      const int col = c0 + wc * 32 + j * 16 + l15;
      #pragma unroll
      for (int r = 0; r < 4; ++r) {
        const int row = t0 + wr * 64 + i * 16 + quad * 4 + r;
        const size_t off = ((size_t)b * Tn + row) * Cn + col;
        dst[off] = src[off] * ss + coef * acc[i][j][r];
      }
    }
  }
}

// dst = s1 + 0.5*cst[lam_idx]*s2/z[row]
__global__ void __launch_bounds__(256) velupd_kernel(
    const float* s1, const float* s2, const float* __restrict__ zb,
    float* dst, const float* __restrict__ cst, int lam_idx) {
  const int blk = blockIdx.x;
  const int row = blk / 3;
  const size_t i = (size_t)row * Cn + (blk % 3) * 256 + threadIdx.x;
  const float vs = 0.5f * cst[lam_idx];
  dst[i] = s1[i] + vs * s2[i] / zb[row];
}

__global__ void __launch_bounds__(256) rot_kernel(
    float* X, float* Pi, float* bX, float* bPi, float c, float sn) {
  const size_t i = (size_t)blockIdx.x * 256 + threadIdx.x;
  const float x = X[i], p = Pi[i], bx = bX[i], bp = bPi[i];
  const float dX = x - bx, dPi = p - bp, sX = x + bx, sPi = p + bp;
  X[i]   = 0.5f * (sX + c * dX + sn * dPi);
  Pi[i]  = 0.5f * (sPi - sn * dX + c * dPi);
  bX[i]  = 0.5f * (sX - c * dX - sn * dPi);
  bPi[i] = 0.5f * (sPi + sn * dX - c * dPi);
}

// Final LayerNorm (fp32 out, in-place capable)
__global__ void __launch_bounds__(256) ln_f32_kernel(
    const float* src, const float* __restrict__ w,
    float* dst, const float* __restrict__ cst, int alpha_idx) {
  const int row = blockIdx.x;
  const int tid = threadIdx.x;
  const float alpha = cst[alpha_idx];
  const float* x = src + (size_t)row * Cn;
  float v0 = alpha * x[tid];
  float v1 = alpha * x[tid + 256];
  float v2 = alpha * x[tid + 512];
  __shared__ float red[256];
  red[tid] = v0 + v1 + v2;
  __syncthreads();
  for (int off = 128; off > 0; off >>= 1) {
    if (tid < off) red[tid] += red[tid + off];
    __syncthreads();
  }
  const float m = red[0] * (1.0f / Cn);
  __syncthreads();
  const float d0 = v0 - m, d1 = v1 - m, d2 = v2 - m;
  red[tid] = d0 * d0 + d1 * d1 + d2 * d2;
  __syncthreads();
  for (int off = 128; off > 0; off >>= 1) {
    if (tid < off) red[tid] += red[tid + off];
    __syncthreads();
  }
  const float rstd = rsqrtf(red[0] * (1.0f / Cn) + LNEPS);
  float* y = dst + (size_t)row * Cn;
  y[tid]       = d0 * rstd * w[tid];
  y[tid + 256] = d1 * rstd * w[tid + 256];
  y[tid + 512] = d2 * rstd * w[tid + 512];
}

extern "C" void kernel_launch(void* const* d_in, const int* in_sizes, int n_in,
                              void* d_out, int out_size, void* d_ws, size_t ws_size,
                              hipStream_t stream) {
  (void)in_sizes; (void)n_in; (void)out_size;
  const float* Xk  = (const float*)d_in[0];
  const float* Pk  = (const float*)d_in[1];
  const float* lw  = (const float*)d_in[2];
  const float* lvw = (const float*)d_in[3];
  const int*   kp  = (const int*)d_in[4];

  float* Xo = (float*)d_out;        // X state in d_out[0:BTC]
  float* Po = Xo + NBTC;            // Pi state in d_out[BTC:2BTC]

  char* wp = (char*)d_ws;
  float*  bX  = (float*)wp;  wp += NBTC * sizeof(float);
  float*  bPi = (float*)wp;  wp += NBTC * sizeof(float);
  bf16_t* XnH = (bf16_t*)wp; wp += NBTC * sizeof(bf16_t);
  bf16_t* XnL = (bf16_t*)wp; wp += NBTC * sizeof(bf16_t);
  ushort* Ehp = (ushort*)wp; wp += (size_t)Bn * NTRI * 16384 * sizeof(ushort);
  ushort* XTh = (ushort*)wp; wp += NBTC * sizeof(ushort);
  float*  zb  = (float*)wp;  wp += (size_t)Bn * Tn * sizeof(float);
  float*  sv  = (float*)wp;  wp += (size_t)Bn * Tn * sizeof(float);
  float*  cst = (float*)wp;  wp += 256;
  const size_t need = (size_t)(wp - (char*)d_ws);
  if (ws_size < need) {
    fprintf(stderr, "[kernel] ws too small: %zu < %zu\n", ws_size, need);
    return;
  }

  const dim3 b256(256);
  const dim3 gLN(Bn * Tn);
  const dim3 gXT(Tn / 64, Cn / 64, Bn);      // (32,12,4)
  const dim3 gZ(NTRI, Bn);                   // triangular 128-tiles x batch
  const dim3 gW(16, 16, Bn);                 // wbuild (skips upper)
  const dim3 gCore(Cn / 64, Tn / 128, Bn);   // (12,16,4) = 768 blocks
  const dim3 gEW(Bn * Tn * 3);
  const float rc = (float)cos(2.0), rs = (float)sin(2.0);   // theta = 2*XI*h

  prep_consts<<<1, 1, 0, stream>>>(kp, cst);

  // ---- Stage A: X-side = Xk, p = Pk (lam*Lam = 1) ----
  ln_hl_kernel<<<gLN, b256, 0, stream>>>(Xk, lw, XnH, XnL, zb, cst, 6);
  xt_kernel<<<gXT, b256, 0, stream>>>((const ushort*)XnH, XTh);
  zpass_mfma<<<gZ, b256, 0, stream>>>(XnH, XnL, Ehp, zb);
  sv_kernel<<<gLN, b256, 0, stream>>>(Pk, zb, sv, cst, 6);
  wbuild_kernel<<<gW, b256, 0, stream>>>(Ehp, sv);
  corepass_mfma<<<gCore, b256, 0, stream>>>(Ehp, XTh, Pk, Po, cst, 0, 0);
  velupd_kernel<<<gEW, b256, 0, stream>>>(Xk, Pk, zb, bX, cst, 6);

  // ---- Stage B: X-side = bX, Pi-side = Po ----
  ln_hl_kernel<<<gLN, b256, 0, stream>>>(bX, lw, XnH, XnL, zb, cst, 6);
  xt_kernel<<<gXT, b256, 0, stream>>>((const ushort*)XnH, XTh);
  zpass_mfma<<<gZ, b256, 0, stream>>>(XnH, XnL, Ehp, zb);
  sv_kernel<<<gLN, b256, 0, stream>>>(Po, zb, sv, cst, 3);
  wbuild_kernel<<<gW, b256, 0, stream>>>(Ehp, sv);
  velupd_kernel<<<gEW, b256, 0, stream>>>(Xk, Po, zb, Xo, cst, 3);
  corepass_mfma<<<gCore, b256, 0, stream>>>(Ehp, XTh, Pk, bPi, cst, 0, 2);

  // ---- rotation mixing ----
  rot_kernel<<<gEW, b256, 0, stream>>>(Xo, Po, bX, bPi, rc, rs);

  // ---- Stage C: X-side = bX, Pi-side = Po ----
  ln_hl_kernel<<<gLN, b256, 0, stream>>>(bX, lw, XnH, XnL, zb, cst, 6);
  xt_kernel<<<gXT, b256, 0, stream>>>((const ushort*)XnH, XTh);
  zpass_mfma<<<gZ, b256, 0, stream>>>(XnH, XnL, Ehp, zb);
  sv_kernel<<<gLN, b256, 0, stream>>>(Po, zb, sv, cst, 3);
  wbuild_kernel<<<gW, b256, 0, stream>>>(Ehp, sv);
  velupd_kernel<<<gEW, b256, 0, stream>>>(Xo, Po, zb, Xo, cst, 3);
  corepass_mfma<<<gCore, b256, 0, stream>>>(Ehp, XTh, bPi, bPi, cst, 6, 2);

  // ---- Stage D: X-side = Xo, p = lam_tk1*bPi ----
  ln_hl_kernel<<<gLN, b256, 0, stream>>>(Xo, lw, XnH, XnL, zb, cst, 6);
  xt_kernel<<<gXT, b256, 0, stream>>>((const ushort*)XnH, XTh);
  zpass_mfma<<<gZ, b256, 0, stream>>>(XnH, XnL, Ehp, zb);
  sv_kernel<<<gLN, b256, 0, stream>>>(bPi, zb, sv, cst, 5);
  wbuild_kernel<<<gW, b256, 0, stream>>>(Ehp, sv);
  corepass_mfma<<<gCore, b256, 0, stream>>>(Ehp, XTh, Po, Po, cst, 6, 4);

  // ---- Final: Pk1 = LN(lam_tk1 * Pi) * ln_v_w (in place on Po) ----
  ln_f32_kernel<<<gLN, b256, 0, stream>>>(Po, lvw, Po, cst, 5);
}

// Round 6
// 809.123 us; speedup vs baseline: 4.5318x; 1.0414x over previous
//
#include <hip/hip_runtime.h>
#include <hip/hip_bf16.h>
#include <cstdio>
#include <cmath>

// Problem constants (B,T,C,NH fixed by the reference)
constexpr int   Bn = 4;
constexpr int   Tn = 2048;
constexpr int   Cn = 768;
constexpr float COEF  = 0.125f / 12.0f;   // SCALE / NH
constexpr float EPSZ  = 1e-8f;
constexpr float LNEPS = 1e-5f;
constexpr int   NTRI  = 136;              // triangular 128-tiles per batch
#define NBTC ((size_t)Bn * Tn * Cn)

typedef __bf16 bf16_t;
typedef bf16_t bf16x8 __attribute__((ext_vector_type(8)));
typedef float  f32x4  __attribute__((ext_vector_type(4)));
typedef ushort u16x8  __attribute__((ext_vector_type(8)));

// async global->LDS, 16B per lane. LDS dest is wave-uniform base + lane*16.
__device__ __forceinline__ void gload16(const void* g, void* l) {
  __builtin_amdgcn_global_load_lds(
      (const __attribute__((address_space(1))) unsigned int*)g,
      (__attribute__((address_space(3))) unsigned int*)l,
      16, 0, 0);
}

__device__ __forceinline__ ushort bf16_bits(float f) {
  bf16_t h = (bf16_t)f;
  return __builtin_bit_cast(ushort, h);
}
__device__ __forceinline__ float bits_to_f(ushort u) {
  return (float)__builtin_bit_cast(bf16_t, u);
}

// cst[] indices: 0 Lam_tk, 1 lam_tk, 2 Lam_tbar, 3 lam_tbar, 4 Lam_tk1, 5 lam_tk1, 6 = 1.0
__global__ void prep_consts(const int* kp, float* cst) {
  if (threadIdx.x == 0 && blockIdx.x == 0) {
    float tk = 1.0f + (float)(*kp);
    float tb = tk + 0.5f;
    float t1 = tk + 1.0f;
    cst[0] = tk * tk * tk; cst[1] = 1.0f / cst[0];
    cst[2] = tb * tb * tb; cst[3] = 1.0f / cst[2];
    cst[4] = t1 * t1 * t1; cst[5] = 1.0f / cst[4];
    cst[6] = 1.0f;
  }
}

// LayerNorm of (alpha*src) with weight w -> hi/lo bf16 split outputs.
// Also zeroes zbuf[row] for the stage's upcoming zpass atomics.
__global__ void __launch_bounds__(256) ln_hl_kernel(
    const float* __restrict__ src, const float* __restrict__ w,
    bf16_t* __restrict__ outH, bf16_t* __restrict__ outL,
    float* __restrict__ zbuf, const float* __restrict__ cst, int alpha_idx) {
  const int row = blockIdx.x;
  const int tid = threadIdx.x;
  const float alpha = cst[alpha_idx];
  const float* x = src + (size_t)row * Cn;
  float v0 = alpha * x[tid];
  float v1 = alpha * x[tid + 256];
  float v2 = alpha * x[tid + 512];
  __shared__ float red[256];
  red[tid] = v0 + v1 + v2;
  __syncthreads();
  for (int off = 128; off > 0; off >>= 1) {
    if (tid < off) red[tid] += red[tid + off];
    __syncthreads();
  }
  const float m = red[0] * (1.0f / Cn);
  __syncthreads();
  const float d0 = v0 - m, d1 = v1 - m, d2 = v2 - m;
  red[tid] = d0 * d0 + d1 * d1 + d2 * d2;
  __syncthreads();
  for (int off = 128; off > 0; off >>= 1) {
    if (tid < off) red[tid] += red[tid + off];
    __syncthreads();
  }
  const float rstd = rsqrtf(red[0] * (1.0f / Cn) + LNEPS);
  const size_t base = (size_t)row * Cn;
  float f0 = d0 * rstd * w[tid];
  float f1 = d1 * rstd * w[tid + 256];
  float f2 = d2 * rstd * w[tid + 512];
  bf16_t h0 = (bf16_t)f0, h1 = (bf16_t)f1, h2 = (bf16_t)f2;
  outH[base + tid]       = h0;  outL[base + tid]       = (bf16_t)(f0 - (float)h0);
  outH[base + tid + 256] = h1;  outL[base + tid + 256] = (bf16_t)(f1 - (float)h1);
  outH[base + tid + 512] = h2;  outL[base + tid + 512] = (bf16_t)(f2 - (float)h2);
  if (tid == 0) zbuf[row] = 0.0f;
}

// Transpose XnH [b][s][c] -> XT [b][c][s] (bf16). grid (Tn/64, Cn/64, Bn).
__global__ void __launch_bounds__(256) xt_kernel(
    const ushort* __restrict__ Xh, ushort* __restrict__ XT) {
  const int b = blockIdx.z;
  const int s0 = blockIdx.x * 64, c0 = blockIdx.y * 64;
  const int tid = threadIdx.x;
  __shared__ ushort t[64][68];
  const ushort* src = Xh + (size_t)b * Tn * Cn;
  ushort* dst = XT + (size_t)b * Cn * Tn;
  #pragma unroll
  for (int p = 0; p < 4; ++p) {
    const int r = p * 16 + (tid >> 4);
    const int c = (tid & 15) * 4;
    const ushort4 v = *(const ushort4*)&src[(size_t)(s0 + r) * Cn + c0 + c];
    *(ushort4*)&t[r][c] = v;
  }
  __syncthreads();
  #pragma unroll
  for (int p = 0; p < 4; ++p) {
    const int cc = p * 16 + (tid >> 4);
    const int ss = (tid & 15) * 4;
    ushort4 o;
    o.x = t[ss + 0][cc]; o.y = t[ss + 1][cc];
    o.z = t[ss + 2][cc]; o.w = t[ss + 3][cc];
    *(ushort4*)&dst[(size_t)(c0 + cc) * Tn + s0 + ss] = o;
  }
}

// Causal gram, 128x64 tile (t x s) for occupancy. E = exp(clip(S*COEF))
// stored single-bf16 into packed 128x128 triangular tiles (pair-packed uint
// stores). Row sums -> atomicAdd zbuf. grid = (272, Bn), block 256.
__global__ void __launch_bounds__(256) zpass_mfma(
    const bf16_t* __restrict__ XnH, const bf16_t* __restrict__ XnL,
    ushort* __restrict__ Ehp, float* __restrict__ zbuf) {
  const int b = blockIdx.y;
  const int l = blockIdx.x;
  int it = (int)(0.5f * (sqrtf(4.0f * (float)l + 1.0f) - 1.0f));
  while ((it + 1) * (it + 2) <= l) ++it;
  while (it * (it + 1) > l) --it;
  const int js = l - it * (it + 1);          // 0 .. 2it+1
  const int t0 = it * 128, s0 = js * 64;
  const int tri = it * (it + 1) / 2 + (js >> 1);
  const int colTileBase = (js & 1) * 64;

  const int tid  = threadIdx.x;
  const int lane = tid & 63;
  const int wv   = tid >> 6;
  const int wr   = wv >> 1, wc = wv & 1;     // wave covers 64t x 32s
  const int quad = lane >> 4, l15 = lane & 15;

  const bf16_t* XbH = XnH + (size_t)b * Tn * Cn;
  const bf16_t* XbL = XnL + (size_t)b * Tn * Cn;
  ushort* EhT = Ehp + ((size_t)b * NTRI + tri) * 16384;

  __shared__ bf16_t Ah[128 * 32], Al[128 * 32];  // 8 KB each
  __shared__ bf16_t Bh[64 * 32],  Bl[64 * 32];   // 4 KB each

  const int srow = lane >> 2;                // 0..15
  const int scol = (lane & 3) * 8;

  f32x4 acc[4][2] = {};

  for (int c0 = 0; c0 < Cn; c0 += 32) {
    __syncthreads();                 // protect LDS while prev chunk still read
    {
      const int rb0 = wv * 16, rb1 = 64 + wv * 16;
      gload16(XbH + (size_t)(t0 + rb0 + srow) * Cn + c0 + scol, Ah + rb0 * 32);
      gload16(XbH + (size_t)(t0 + rb1 + srow) * Cn + c0 + scol, Ah + rb1 * 32);
      gload16(XbL + (size_t)(t0 + rb0 + srow) * Cn + c0 + scol, Al + rb0 * 32);
      gload16(XbL + (size_t)(t0 + rb1 + srow) * Cn + c0 + scol, Al + rb1 * 32);
      gload16(XbH + (size_t)(s0 + rb0 + srow) * Cn + c0 + scol, Bh + rb0 * 32);
      gload16(XbL + (size_t)(s0 + rb0 + srow) * Cn + c0 + scol, Bl + rb0 * 32);
    }
    __syncthreads();                 // drain vmcnt + all slabs present

    bf16x8 ah[4], al[4], bh[2], bl[2];
    #pragma unroll
    for (int i = 0; i < 4; ++i) {
      ah[i] = *(const bf16x8*)&Ah[(wr * 64 + i * 16 + l15) * 32 + quad * 8];
      al[i] = *(const bf16x8*)&Al[(wr * 64 + i * 16 + l15) * 32 + quad * 8];
    }
    #pragma unroll
    for (int j = 0; j < 2; ++j) {
      bh[j] = *(const bf16x8*)&Bh[(wc * 32 + j * 16 + l15) * 32 + quad * 8];
      bl[j] = *(const bf16x8*)&Bl[(wc * 32 + j * 16 + l15) * 32 + quad * 8];
    }
    #pragma unroll
    for (int i = 0; i < 4; ++i)
      #pragma unroll
      for (int j = 0; j < 2; ++j) {
        acc[i][j] = __builtin_amdgcn_mfma_f32_16x16x32_bf16(ah[i], bh[j], acc[i][j], 0, 0, 0);
        acc[i][j] = __builtin_amdgcn_mfma_f32_16x16x32_bf16(al[i], bh[j], acc[i][j], 0, 0, 0);
        acc[i][j] = __builtin_amdgcn_mfma_f32_16x16x32_bf16(ah[i], bl[j], acc[i][j], 0, 0, 0);
      }
  }

  float zacc[4][4];
  #pragma unroll
  for (int i = 0; i < 4; ++i)
    #pragma unroll
    for (int r = 0; r < 4; ++r) zacc[i][r] = 0.0f;

  #pragma unroll
  for (int i = 0; i < 4; ++i) {
    #pragma unroll
    for (int j = 0; j < 2; ++j) {
      const int inCol = colTileBase + wc * 32 + j * 16 + l15;
      const int gcol  = s0 + wc * 32 + j * 16 + l15;
      #pragma unroll
      for (int r = 0; r < 4; ++r) {
        const int rowL = wr * 64 + i * 16 + quad * 4 + r;
        float sV = acc[i][j][r] * COEF;
        sV = fminf(fmaxf(sV, -60.f), 60.f);
        const float e = (gcol <= t0 + rowL) ? __expf(sV) : 0.f;
        const float pe = __shfl_xor(e, 1);
        if ((lane & 1) == 0) {
          const uint pk = (uint)bf16_bits(e) | ((uint)bf16_bits(pe) << 16);
          *(uint*)&EhT[rowL * 128 + inCol] = pk;
        }
        zacc[i][r] += e;
      }
    }
  }
  #pragma unroll
  for (int i = 0; i < 4; ++i)
    #pragma unroll
    for (int r = 0; r < 4; ++r) {
      float v = zacc[i][r];
      v += __shfl_xor(v, 1);
      v += __shfl_xor(v, 2);
      v += __shfl_xor(v, 4);
      v += __shfl_xor(v, 8);
      if (l15 == 0)
        atomicAdd(&zbuf[b * Tn + t0 + wr * 64 + i * 16 + quad * 4 + r], v);
    }
}

// Finalize z (raw sum -> max(sum/T, EPS)) and compute sv = |p|^2 / (z^2 + EPS).
__global__ void __launch_bounds__(256) sv_kernel(
    const float* __restrict__ Pisrc, float* __restrict__ zbuf,
    float* __restrict__ sv, const float* __restrict__ cst, int ps_idx) {
  const int row = blockIdx.x;
  const int tid = threadIdx.x;
  const float* p = Pisrc + (size_t)row * Cn;
  const float v0 = p[tid], v1 = p[tid + 256], v2 = p[tid + 512];
  __shared__ float red[256];
  red[tid] = v0 * v0 + v1 * v1 + v2 * v2;
  __syncthreads();
  for (int off = 128; off > 0; off >>= 1) {
    if (tid < off) red[tid] += red[tid + off];
    __syncthreads();
  }
  if (tid == 0) {
    const float ps = cst[ps_idx];
    const float a = red[0] * ps * ps;
    const float zf = fmaxf(zbuf[row] * (1.0f / Tn), EPSZ);
    zbuf[row] = zf;
    sv[row] = a / (zf * zf + EPSZ);
  }
}

// In-place W-build: E[t,s] *= (sv[t] + sv[s] - 2), packed single-bf16 tiles.
// grid = (16 s-tiles, 16 t-tiles, Bn); skip strictly-upper tiles.
__global__ void __launch_bounds__(256) wbuild_kernel(
    ushort* __restrict__ Ehp, const float* __restrict__ sv) {
  const int st = blockIdx.x, it = blockIdx.y, b = blockIdx.z;
  if (st > it) return;
  const int tri = it * (it + 1) / 2 + st;
  ushort* EhT = Ehp + ((size_t)b * NTRI + tri) * 16384;
  const float* svB = sv + b * Tn;

  const int tid = threadIdx.x;
  const int r  = tid >> 1;            // 0..127
  const int ch = (tid & 1) * 64;      // col half
  const float svt2 = svB[it * 128 + r] - 2.0f;
  const int base = r * 128 + ch;
  #pragma unroll
  for (int v = 0; v < 8; ++v) {
    u16x8 h8 = *(const u16x8*)&EhT[base + v * 8];
    const float4 sa = *(const float4*)(svB + st * 128 + ch + v * 8);
    const float4 sb = *(const float4*)(svB + st * 128 + ch + v * 8 + 4);
    const float ss[8] = {sa.x, sa.y, sa.z, sa.w, sb.x, sb.y, sb.z, sb.w};
    u16x8 nh;
    #pragma unroll
    for (int q = 0; q < 8; ++q) {
      const float w = bits_to_f(h8[q]) * (svt2 + ss[q]);
      nh[q] = bf16_bits(w);
    }
    *(u16x8*)&EhT[base + v * 8] = nh;
  }
}

// core GEMM + fused elementwise epilogues.
// dst = src*cst[ss_idx] + coef * W @ Xn, then per MODE:
//  0 (stage A): eC(bX) = eA(Xk) + vs*src/z
//  1 (stage B): xo = eA(Xk)+vs*eB(Po)/z; rotation of (xo, eB, eC(bX), d)
//               -> writes eD(Xo), eB(Po), eC(bX), dst(bPi)
//  2 (stage C): eA(Xo) += vs*eB(Po)/z
//  3 (stage D): plain
// Tile 128t x 64c; grid = (12, 16, Bn), big-K first. src/dst may alias.
template <int MODE>
__global__ void __launch_bounds__(256) corepass_mfma(
    const ushort* __restrict__ Whp, const ushort* __restrict__ XT,
    const float* src, float* dst,
    const float* __restrict__ cst, int ss_idx, int lam_idx,
    float* eA, float* eB, float* eC, float* eD,
    const float* __restrict__ zb, int vel_idx, float rc, float rs) {
  const int b  = blockIdx.z;
  const int it = (int)gridDim.y - 1 - (int)blockIdx.y;   // big K first
  const int ic = blockIdx.x;
  const int t0 = it * 128, c0 = ic * 64;

  const int tid  = threadIdx.x;
  const int lane = tid & 63;
  const int wv   = tid >> 6;
  const int wr   = wv >> 1, wc = wv & 1;   // wave covers 64t x 32c
  const int quad = lane >> 4, l15 = lane & 15;

  const ushort* WhB = Whp + (size_t)b * NTRI * 16384;
  const ushort* XTb = XT + (size_t)b * Cn * Tn;

  __shared__ ushort Ah[128 * 32];   // W slab  (8 KB)
  __shared__ ushort Bh[64 * 32];    // X^T slab (4 KB)

  const int srow = lane >> 2;
  const int scol = (lane & 3) * 8;
  const int triBase = it * (it + 1) / 2;

  f32x4 acc[4][2] = {};
  const int chunks = (it + 1) * 4;
  for (int kc = 0; kc < chunks; ++kc) {
    const int ss0 = kc * 32;
    const int stile = kc >> 2, soff = (kc & 3) * 32;
    const ushort* tileH = WhB + (size_t)(triBase + stile) * 16384 + soff;

    __syncthreads();                 // prev chunk's LDS reads done
    #pragma unroll
    for (int j = 0; j < 2; ++j) {
      const int rb = wv * 16 + j * 64;
      gload16(tileH + (size_t)(rb + srow) * 128 + scol, Ah + rb * 32);
    }
    gload16(XTb + (size_t)(c0 + wv * 16 + srow) * Tn + ss0 + scol,
            Bh + wv * 16 * 32);
    __syncthreads();                 // drain vmcnt

    bf16x8 ah[4], bh[2];
    #pragma unroll
    for (int i = 0; i < 4; ++i)
      ah[i] = *(const bf16x8*)&Ah[(wr * 64 + i * 16 + l15) * 32 + quad * 8];
    #pragma unroll
    for (int j = 0; j < 2; ++j)
      bh[j] = *(const bf16x8*)&Bh[(wc * 32 + j * 16 + l15) * 32 + quad * 8];
    #pragma unroll
    for (int i = 0; i < 4; ++i)
      #pragma unroll
      for (int j = 0; j < 2; ++j)
        acc[i][j] = __builtin_amdgcn_mfma_f32_16x16x32_bf16(ah[i], bh[j], acc[i][j], 0, 0, 0);
  }

  const float coef = 0.5f * cst[lam_idx] * (1.0f / (2.0f * Tn));
  const float ssc = cst[ss_idx];
  const float vs = 0.5f * cst[vel_idx];
  #pragma unroll
  for (int i = 0; i < 4; ++i) {
    #pragma unroll
    for (int j = 0; j < 2; ++j) {
      const int col = c0 + wc * 32 + j * 16 + l15;
      #pragma unroll
      for (int r = 0; r < 4; ++r) {
        const int row = t0 + wr * 64 + i * 16 + quad * 4 + r;
        const size_t off = ((size_t)b * Tn + row) * Cn + col;
        const float srcv = src[off];
        const float d = srcv * ssc + coef * acc[i][j][r];
        if (MODE == 0) {
          dst[off] = d;
          eC[off] = eA[off] + vs * srcv / zb[b * Tn + row];
        } else if (MODE == 1) {
          const float z  = zb[b * Tn + row];
          const float po = eB[off];
          const float xo = eA[off] + vs * po / z;
          const float bx = eC[off];
          const float dX = xo - bx, dPi = po - d;
          const float sX = xo + bx, sPi = po + d;
          eD[off]  = 0.5f * (sX + rc * dX + rs * dPi);   // Xo
          eB[off]  = 0.5f * (sPi - rs * dX + rc * dPi);  // Po
          eC[off]  = 0.5f * (sX - rc * dX - rs * dPi);   // bX
          dst[off] = 0.5f * (sPi + rs * dX - rc * dPi);  // bPi
        } else if (MODE == 2) {
          dst[off] = d;
          eA[off] = eA[off] + vs * eB[off] / zb[b * Tn + row];
        } else {
          dst[off] = d;
        }
      }
    }
  }
}

// Final LayerNorm (fp32 out, in-place capable)
__global__ void __launch_bounds__(256) ln_f32_kernel(
    const float* src, const float* __restrict__ w,
    float* dst, const float* __restrict__ cst, int alpha_idx) {
  const int row = blockIdx.x;
  const int tid = threadIdx.x;
  const float alpha = cst[alpha_idx];
  const float* x = src + (size_t)row * Cn;
  float v0 = alpha * x[tid];
  float v1 = alpha * x[tid + 256];
  float v2 = alpha * x[tid + 512];
  __shared__ float red[256];
  red[tid] = v0 + v1 + v2;
  __syncthreads();
  for (int off = 128; off > 0; off >>= 1) {
    if (tid < off) red[tid] += red[tid + off];
    __syncthreads();
  }
  const float m = red[0] * (1.0f / Cn);
  __syncthreads();
  const float d0 = v0 - m, d1 = v1 - m, d2 = v2 - m;
  red[tid] = d0 * d0 + d1 * d1 + d2 * d2;
  __syncthreads();
  for (int off = 128; off > 0; off >>= 1) {
    if (tid < off) red[tid] += red[tid + off];
    __syncthreads();
  }
  const float rstd = rsqrtf(red[0] * (1.0f / Cn) + LNEPS);
  float* y = dst + (size_t)row * Cn;
  y[tid]       = d0 * rstd * w[tid];
  y[tid + 256] = d1 * rstd * w[tid + 256];
  y[tid + 512] = d2 * rstd * w[tid + 512];
}

extern "C" void kernel_launch(void* const* d_in, const int* in_sizes, int n_in,
                              void* d_out, int out_size, void* d_ws, size_t ws_size,
                              hipStream_t stream) {
  (void)in_sizes; (void)n_in; (void)out_size;
  const float* Xk  = (const float*)d_in[0];
  const float* Pk  = (const float*)d_in[1];
  const float* lw  = (const float*)d_in[2];
  const float* lvw = (const float*)d_in[3];
  const int*   kp  = (const int*)d_in[4];

  float* Xo = (float*)d_out;        // X state in d_out[0:BTC]
  float* Po = Xo + NBTC;            // Pi state in d_out[BTC:2BTC]

  char* wp = (char*)d_ws;
  float*  bX  = (float*)wp;  wp += NBTC * sizeof(float);
  float*  bPi = (float*)wp;  wp += NBTC * sizeof(float);
  bf16_t* XnH = (bf16_t*)wp; wp += NBTC * sizeof(bf16_t);
  bf16_t* XnL = (bf16_t*)wp; wp += NBTC * sizeof(bf16_t);
  ushort* Ehp = (ushort*)wp; wp += (size_t)Bn * NTRI * 16384 * sizeof(ushort);
  ushort* XTh = (ushort*)wp; wp += NBTC * sizeof(ushort);
  float*  zb  = (float*)wp;  wp += (size_t)Bn * Tn * sizeof(float);
  float*  sv  = (float*)wp;  wp += (size_t)Bn * Tn * sizeof(float);
  float*  cst = (float*)wp;  wp += 256;
  const size_t need = (size_t)(wp - (char*)d_ws);
  if (ws_size < need) {
    fprintf(stderr, "[kernel] ws too small: %zu < %zu\n", ws_size, need);
    return;
  }

  const dim3 b256(256);
  const dim3 gLN(Bn * Tn);
  const dim3 gXT(Tn / 64, Cn / 64, Bn);      // (32,12,4)
  const dim3 gZ(272, Bn);                    // causal 128x64 tiles x batch
  const dim3 gW(16, 16, Bn);                 // wbuild (skips upper)
  const dim3 gCore(Cn / 64, Tn / 128, Bn);   // (12,16,4) = 768 blocks
  const float rc = (float)cos(2.0), rs = (float)sin(2.0);   // theta = 2*XI*h

  prep_consts<<<1, 1, 0, stream>>>(kp, cst);

  // ---- Stage A: X-side = Xk, p = Pk (lam*Lam = 1) ----
  ln_hl_kernel<<<gLN, b256, 0, stream>>>(Xk, lw, XnH, XnL, zb, cst, 6);
  xt_kernel<<<gXT, b256, 0, stream>>>((const ushort*)XnH, XTh);
  zpass_mfma<<<gZ, b256, 0, stream>>>(XnH, XnL, Ehp, zb);
  sv_kernel<<<gLN, b256, 0, stream>>>(Pk, zb, sv, cst, 6);
  wbuild_kernel<<<gW, b256, 0, stream>>>(Ehp, sv);
  corepass_mfma<0><<<gCore, b256, 0, stream>>>(Ehp, XTh, Pk, Po, cst, 0, 0,
      (float*)Xk, nullptr, bX, nullptr, zb, 6, rc, rs);

  // ---- Stage B: X-side = bX, Pi-side = Po; fused velupd-B + rotation ----
  ln_hl_kernel<<<gLN, b256, 0, stream>>>(bX, lw, XnH, XnL, zb, cst, 6);
  xt_kernel<<<gXT, b256, 0, stream>>>((const ushort*)XnH, XTh);
  zpass_mfma<<<gZ, b256, 0, stream>>>(XnH, XnL, Ehp, zb);
  sv_kernel<<<gLN, b256, 0, stream>>>(Po, zb, sv, cst, 3);
  wbuild_kernel<<<gW, b256, 0, stream>>>(Ehp, sv);
  corepass_mfma<1><<<gCore, b256, 0, stream>>>(Ehp, XTh, Pk, bPi, cst, 0, 2,
      (float*)Xk, Po, bX, Xo, zb, 3, rc, rs);

  // ---- Stage C: X-side = bX, Pi-side = Po; fused velupd-C ----
  ln_hl_kernel<<<gLN, b256, 0, stream>>>(bX, lw, XnH, XnL, zb, cst, 6);
  xt_kernel<<<gXT, b256, 0, stream>>>((const ushort*)XnH, XTh);
  zpass_mfma<<<gZ, b256, 0, stream>>>(XnH, XnL, Ehp, zb);
  sv_kernel<<<gLN, b256, 0, stream>>>(Po, zb, sv, cst, 3);
  wbuild_kernel<<<gW, b256, 0, stream>>>(Ehp, sv);
  corepass_mfma<2><<<gCore, b256, 0, stream>>>(Ehp, XTh, bPi, bPi, cst, 6, 2,
      Xo, Po, nullptr, nullptr, zb, 3, rc, rs);

  // ---- Stage D: X-side = Xo, p = lam_tk1*bPi ----
  ln_hl_kernel<<<gLN, b256, 0, stream>>>(Xo, lw, XnH, XnL, zb, cst, 6);
  xt_kernel<<<gXT, b256, 0, stream>>>((const ushort*)XnH, XTh);
  zpass_mfma<<<gZ, b256, 0, stream>>>(XnH, XnL, Ehp, zb);
  sv_kernel<<<gLN, b256, 0, stream>>>(bPi, zb, sv, cst, 5);
  wbuild_kernel<<<gW, b256, 0, stream>>>(Ehp, sv);
  corepass_mfma<3><<<gCore, b256, 0, stream>>>(Ehp, XTh, Po, Po, cst, 6, 4,
      nullptr, nullptr, nullptr, nullptr, zb, 6, rc, rs);

  // ---- Final: Pk1 = LN(lam_tk1 * Pi) * ln_v_w (in place on Po) ----
  ln_f32_kernel<<<gLN, b256, 0, stream>>>(Po, lvw, Po, cst, 5);
}

// Round 7
// 689.959 us; speedup vs baseline: 5.3145x; 1.1727x over previous
//
#include <hip/hip_runtime.h>
#include <hip/hip_bf16.h>
#include <cstdio>
#include <cmath>

// Problem constants (B,T,C,NH fixed by the reference)
constexpr int   Bn = 4;
constexpr int   Tn = 2048;
constexpr int   Cn = 768;
constexpr float COEF  = 0.125f / 12.0f;   // SCALE / NH
constexpr float EPSZ  = 1e-8f;
constexpr float LNEPS = 1e-5f;
constexpr int   NTRI  = 136;              // triangular 128-tiles per batch
#define NBTC ((size_t)Bn * Tn * Cn)

typedef __bf16 bf16_t;
typedef _Float16 f16_t;
typedef bf16_t bf16x8 __attribute__((ext_vector_type(8)));
typedef f16_t  f16x8  __attribute__((ext_vector_type(8)));
typedef float  f32x4  __attribute__((ext_vector_type(4)));
typedef ushort u16x8  __attribute__((ext_vector_type(8)));

// async global->LDS, 16B per lane. LDS dest is wave-uniform base + lane*16.
__device__ __forceinline__ void gload16(const void* g, void* l) {
  __builtin_amdgcn_global_load_lds(
      (const __attribute__((address_space(1))) unsigned int*)g,
      (__attribute__((address_space(3))) unsigned int*)l,
      16, 0, 0);
}

__device__ __forceinline__ ushort bf16_bits(float f) {
  bf16_t h = (bf16_t)f;
  return __builtin_bit_cast(ushort, h);
}
__device__ __forceinline__ float bits_to_f(ushort u) {
  return (float)__builtin_bit_cast(bf16_t, u);
}

// cst[] indices: 0 Lam_tk, 1 lam_tk, 2 Lam_tbar, 3 lam_tbar, 4 Lam_tk1, 5 lam_tk1, 6 = 1.0
__global__ void prep_consts(const int* kp, float* cst) {
  if (threadIdx.x == 0 && blockIdx.x == 0) {
    float tk = 1.0f + (float)(*kp);
    float tb = tk + 0.5f;
    float t1 = tk + 1.0f;
    cst[0] = tk * tk * tk; cst[1] = 1.0f / cst[0];
    cst[2] = tb * tb * tb; cst[3] = 1.0f / cst[2];
    cst[4] = t1 * t1 * t1; cst[5] = 1.0f / cst[4];
    cst[6] = 1.0f;
  }
}

// LayerNorm of (alpha*src) with weight w -> fp16 (gram operand) + bf16
// (corepass operand) outputs. Also zeroes zbuf[row] for zpass atomics.
__global__ void __launch_bounds__(256) ln_dual_kernel(
    const float* __restrict__ src, const float* __restrict__ w,
    f16_t* __restrict__ outF, bf16_t* __restrict__ outB,
    float* __restrict__ zbuf, const float* __restrict__ cst, int alpha_idx) {
  const int row = blockIdx.x;
  const int tid = threadIdx.x;
  const float alpha = cst[alpha_idx];
  const float* x = src + (size_t)row * Cn;
  float v0 = alpha * x[tid];
  float v1 = alpha * x[tid + 256];
  float v2 = alpha * x[tid + 512];
  __shared__ float red[256];
  red[tid] = v0 + v1 + v2;
  __syncthreads();
  for (int off = 128; off > 0; off >>= 1) {
    if (tid < off) red[tid] += red[tid + off];
    __syncthreads();
  }
  const float m = red[0] * (1.0f / Cn);
  __syncthreads();
  const float d0 = v0 - m, d1 = v1 - m, d2 = v2 - m;
  red[tid] = d0 * d0 + d1 * d1 + d2 * d2;
  __syncthreads();
  for (int off = 128; off > 0; off >>= 1) {
    if (tid < off) red[tid] += red[tid + off];
    __syncthreads();
  }
  const float rstd = rsqrtf(red[0] * (1.0f / Cn) + LNEPS);
  const size_t base = (size_t)row * Cn;
  float f0 = d0 * rstd * w[tid];
  float f1 = d1 * rstd * w[tid + 256];
  float f2 = d2 * rstd * w[tid + 512];
  outF[base + tid]       = (f16_t)f0;  outB[base + tid]       = (bf16_t)f0;
  outF[base + tid + 256] = (f16_t)f1;  outB[base + tid + 256] = (bf16_t)f1;
  outF[base + tid + 512] = (f16_t)f2;  outB[base + tid + 512] = (bf16_t)f2;
  if (tid == 0) zbuf[row] = 0.0f;
}

// Transpose Xnb [b][s][c] -> XT [b][c][s] (bf16). grid (Tn/64, Cn/64, Bn).
__global__ void __launch_bounds__(256) xt_kernel(
    const ushort* __restrict__ Xh, ushort* __restrict__ XT) {
  const int b = blockIdx.z;
  const int s0 = blockIdx.x * 64, c0 = blockIdx.y * 64;
  const int tid = threadIdx.x;
  __shared__ ushort t[64][68];
  const ushort* src = Xh + (size_t)b * Tn * Cn;
  ushort* dst = XT + (size_t)b * Cn * Tn;
  #pragma unroll
  for (int p = 0; p < 4; ++p) {
    const int r = p * 16 + (tid >> 4);
    const int c = (tid & 15) * 4;
    const ushort4 v = *(const ushort4*)&src[(size_t)(s0 + r) * Cn + c0 + c];
    *(ushort4*)&t[r][c] = v;
  }
  __syncthreads();
  #pragma unroll
  for (int p = 0; p < 4; ++p) {
    const int cc = p * 16 + (tid >> 4);
    const int ss = (tid & 15) * 4;
    ushort4 o;
    o.x = t[ss + 0][cc]; o.y = t[ss + 1][cc];
    o.z = t[ss + 2][cc]; o.w = t[ss + 3][cc];
    *(ushort4*)&dst[(size_t)(c0 + cc) * Tn + s0 + ss] = o;
  }
}

// Causal gram, 128x64 tile, single-fp16 MFMA. E = exp(clip(S*COEF)) stored
// single-bf16 into packed 128x128 triangular tiles (pair-packed uint stores).
// Row sums -> atomicAdd zbuf. grid = (272, Bn), block 256.
__global__ void __launch_bounds__(256) zpass_mfma(
    const f16_t* __restrict__ XnF,
    ushort* __restrict__ Ehp, float* __restrict__ zbuf) {
  const int b = blockIdx.y;
  const int l = blockIdx.x;
  int it = (int)(0.5f * (sqrtf(4.0f * (float)l + 1.0f) - 1.0f));
  while ((it + 1) * (it + 2) <= l) ++it;
  while (it * (it + 1) > l) --it;
  const int js = l - it * (it + 1);          // 0 .. 2it+1
  const int t0 = it * 128, s0 = js * 64;
  const int tri = it * (it + 1) / 2 + (js >> 1);
  const int colTileBase = (js & 1) * 64;

  const int tid  = threadIdx.x;
  const int lane = tid & 63;
  const int wv   = tid >> 6;
  const int wr   = wv >> 1, wc = wv & 1;     // wave covers 64t x 32s
  const int quad = lane >> 4, l15 = lane & 15;

  const f16_t* XbF = XnF + (size_t)b * Tn * Cn;
  ushort* EhT = Ehp + ((size_t)b * NTRI + tri) * 16384;

  __shared__ f16_t Af[128 * 32];   // 8 KB
  __shared__ f16_t Bf[64 * 32];    // 4 KB

  const int srow = lane >> 2;                // 0..15
  const int scol = (lane & 3) * 8;

  f32x4 acc[4][2] = {};

  for (int c0 = 0; c0 < Cn; c0 += 32) {
    __syncthreads();                 // protect LDS while prev chunk still read
    {
      const int rb0 = wv * 16, rb1 = 64 + wv * 16;
      gload16(XbF + (size_t)(t0 + rb0 + srow) * Cn + c0 + scol, Af + rb0 * 32);
      gload16(XbF + (size_t)(t0 + rb1 + srow) * Cn + c0 + scol, Af + rb1 * 32);
      gload16(XbF + (size_t)(s0 + rb0 + srow) * Cn + c0 + scol, Bf + rb0 * 32);
    }
    __syncthreads();                 // drain vmcnt + all slabs present

    f16x8 af[4], bf[2];
    #pragma unroll
    for (int i = 0; i < 4; ++i)
      af[i] = *(const f16x8*)&Af[(wr * 64 + i * 16 + l15) * 32 + quad * 8];
    #pragma unroll
    for (int j = 0; j < 2; ++j)
      bf[j] = *(const f16x8*)&Bf[(wc * 32 + j * 16 + l15) * 32 + quad * 8];
    #pragma unroll
    for (int i = 0; i < 4; ++i)
      #pragma unroll
      for (int j = 0; j < 2; ++j)
        acc[i][j] = __builtin_amdgcn_mfma_f32_16x16x32_f16(af[i], bf[j], acc[i][j], 0, 0, 0);
  }

  float zacc[4][4];
  #pragma unroll
  for (int i = 0; i < 4; ++i)
    #pragma unroll
    for (int r = 0; r < 4; ++r) zacc[i][r] = 0.0f;

  #pragma unroll
  for (int i = 0; i < 4; ++i) {
    #pragma unroll
    for (int j = 0; j < 2; ++j) {
      const int inCol = colTileBase + wc * 32 + j * 16 + l15;
      const int gcol  = s0 + wc * 32 + j * 16 + l15;
      #pragma unroll
      for (int r = 0; r < 4; ++r) {
        const int rowL = wr * 64 + i * 16 + quad * 4 + r;
        float sV = acc[i][j][r] * COEF;
        sV = fminf(fmaxf(sV, -60.f), 60.f);
        const float e = (gcol <= t0 + rowL) ? __expf(sV) : 0.f;
        const float pe = __shfl_xor(e, 1);
        if ((lane & 1) == 0) {
          const uint pk = (uint)bf16_bits(e) | ((uint)bf16_bits(pe) << 16);
          *(uint*)&EhT[rowL * 128 + inCol] = pk;
        }
        zacc[i][r] += e;
      }
    }
  }
  #pragma unroll
  for (int i = 0; i < 4; ++i)
    #pragma unroll
    for (int r = 0; r < 4; ++r) {
      float v = zacc[i][r];
      v += __shfl_xor(v, 1);
      v += __shfl_xor(v, 2);
      v += __shfl_xor(v, 4);
      v += __shfl_xor(v, 8);
      if (l15 == 0)
        atomicAdd(&zbuf[b * Tn + t0 + wr * 64 + i * 16 + quad * 4 + r], v);
    }
}

// Finalize z (raw sum -> max(sum/T, EPS)) and compute sv = |p|^2 / (z^2 + EPS).
__global__ void __launch_bounds__(256) sv_kernel(
    const float* __restrict__ Pisrc, float* __restrict__ zbuf,
    float* __restrict__ sv, const float* __restrict__ cst, int ps_idx) {
  const int row = blockIdx.x;
  const int tid = threadIdx.x;
  const float* p = Pisrc + (size_t)row * Cn;
  const float v0 = p[tid], v1 = p[tid + 256], v2 = p[tid + 512];
  __shared__ float red[256];
  red[tid] = v0 * v0 + v1 * v1 + v2 * v2;
  __syncthreads();
  for (int off = 128; off > 0; off >>= 1) {
    if (tid < off) red[tid] += red[tid + off];
    __syncthreads();
  }
  if (tid == 0) {
    const float ps = cst[ps_idx];
    const float a = red[0] * ps * ps;
    const float zf = fmaxf(zbuf[row] * (1.0f / Tn), EPSZ);
    zbuf[row] = zf;
    sv[row] = a / (zf * zf + EPSZ);
  }
}

// In-place W-build: E[t,s] *= (sv[t] + sv[s] - 2), packed single-bf16 tiles.
// grid = (16 s-tiles, 16 t-tiles, Bn); skip strictly-upper tiles.
__global__ void __launch_bounds__(256) wbuild_kernel(
    ushort* __restrict__ Ehp, const float* __restrict__ sv) {
  const int st = blockIdx.x, it = blockIdx.y, b = blockIdx.z;
  if (st > it) return;
  const int tri = it * (it + 1) / 2 + st;
  ushort* EhT = Ehp + ((size_t)b * NTRI + tri) * 16384;
  const float* svB = sv + b * Tn;

  const int tid = threadIdx.x;
  const int r  = tid >> 1;            // 0..127
  const int ch = (tid & 1) * 64;      // col half
  const float svt2 = svB[it * 128 + r] - 2.0f;
  const int base = r * 128 + ch;
  #pragma unroll
  for (int v = 0; v < 8; ++v) {
    u16x8 h8 = *(const u16x8*)&EhT[base + v * 8];
    const float4 sa = *(const float4*)(svB + st * 128 + ch + v * 8);
    const float4 sb = *(const float4*)(svB + st * 128 + ch + v * 8 + 4);
    const float ss[8] = {sa.x, sa.y, sa.z, sa.w, sb.x, sb.y, sb.z, sb.w};
    u16x8 nh;
    #pragma unroll
    for (int q = 0; q < 8; ++q) {
      const float w = bits_to_f(h8[q]) * (svt2 + ss[q]);
      nh[q] = bf16_bits(w);
    }
    *(u16x8*)&EhT[base + v * 8] = nh;
  }
}

// core GEMM + fused elementwise epilogues.
// dst = src*cst[ss_idx] + coef * W @ Xn, then per MODE:
//  0 (stage A): eC(bX) = eA(Xk) + vs*src/z
//  1 (stage B): xo = eA(Xk)+vs*eB(Po)/z; rotation of (xo, eB, eC(bX), d)
//               -> writes eD(Xo), eB(Po), eC(bX), dst(bPi)
//  2 (stage C): eA(Xo) += vs*eB(Po)/z
//  3 (stage D): plain
// Tile 128t x 64c; grid = (12, 16, Bn), big-K first. src/dst may alias.
template <int MODE>
__global__ void __launch_bounds__(256) corepass_mfma(
    const ushort* __restrict__ Whp, const ushort* __restrict__ XT,
    const float* src, float* dst,
    const float* __restrict__ cst, int ss_idx, int lam_idx,
    float* eA, float* eB, float* eC, float* eD,
    const float* __restrict__ zb, int vel_idx, float rc, float rs) {
  const int b  = blockIdx.z;
  const int it = (int)gridDim.y - 1 - (int)blockIdx.y;   // big K first
  const int ic = blockIdx.x;
  const int t0 = it * 128, c0 = ic * 64;

  const int tid  = threadIdx.x;
  const int lane = tid & 63;
  const int wv   = tid >> 6;
  const int wr   = wv >> 1, wc = wv & 1;   // wave covers 64t x 32c
  const int quad = lane >> 4, l15 = lane & 15;

  const ushort* WhB = Whp + (size_t)b * NTRI * 16384;
  const ushort* XTb = XT + (size_t)b * Cn * Tn;

  __shared__ ushort Ah[128 * 32];   // W slab  (8 KB)
  __shared__ ushort Bh[64 * 32];    // X^T slab (4 KB)

  const int srow = lane >> 2;
  const int scol = (lane & 3) * 8;
  const int triBase = it * (it + 1) / 2;

  f32x4 acc[4][2] = {};
  const int chunks = (it + 1) * 4;
  for (int kc = 0; kc < chunks; ++kc) {
    const int ss0 = kc * 32;
    const int stile = kc >> 2, soff = (kc & 3) * 32;
    const ushort* tileH = WhB + (size_t)(triBase + stile) * 16384 + soff;

    __syncthreads();                 // prev chunk's LDS reads done
    #pragma unroll
    for (int j = 0; j < 2; ++j) {
      const int rb = wv * 16 + j * 64;
      gload16(tileH + (size_t)(rb + srow) * 128 + scol, Ah + rb * 32);
    }
    gload16(XTb + (size_t)(c0 + wv * 16 + srow) * Tn + ss0 + scol,
            Bh + wv * 16 * 32);
    __syncthreads();                 // drain vmcnt

    bf16x8 ah[4], bh[2];
    #pragma unroll
    for (int i = 0; i < 4; ++i)
      ah[i] = *(const bf16x8*)&Ah[(wr * 64 + i * 16 + l15) * 32 + quad * 8];
    #pragma unroll
    for (int j = 0; j < 2; ++j)
      bh[j] = *(const bf16x8*)&Bh[(wc * 32 + j * 16 + l15) * 32 + quad * 8];
    #pragma unroll
    for (int i = 0; i < 4; ++i)
      #pragma unroll
      for (int j = 0; j < 2; ++j)
        acc[i][j] = __builtin_amdgcn_mfma_f32_16x16x32_bf16(ah[i], bh[j], acc[i][j], 0, 0, 0);
  }

  const float coef = 0.5f * cst[lam_idx] * (1.0f / (2.0f * Tn));
  const float ssc = cst[ss_idx];
  const float vs = 0.5f * cst[vel_idx];
  #pragma unroll
  for (int i = 0; i < 4; ++i) {
    #pragma unroll
    for (int j = 0; j < 2; ++j) {
      const int col = c0 + wc * 32 + j * 16 + l15;
      #pragma unroll
      for (int r = 0; r < 4; ++r) {
        const int row = t0 + wr * 64 + i * 16 + quad * 4 + r;
        const size_t off = ((size_t)b * Tn + row) * Cn + col;
        const float srcv = src[off];
        const float d = srcv * ssc + coef * acc[i][j][r];
        if (MODE == 0) {
          dst[off] = d;
          eC[off] = eA[off] + vs * srcv / zb[b * Tn + row];
        } else if (MODE == 1) {
          const float z  = zb[b * Tn + row];
          const float po = eB[off];
          const float xo = eA[off] + vs * po / z;
          const float bx = eC[off];
          const float dX = xo - bx, dPi = po - d;
          const float sX = xo + bx, sPi = po + d;
          eD[off]  = 0.5f * (sX + rc * dX + rs * dPi);   // Xo
          eB[off]  = 0.5f * (sPi - rs * dX + rc * dPi);  // Po
          eC[off]  = 0.5f * (sX - rc * dX - rs * dPi);   // bX
          dst[off] = 0.5f * (sPi + rs * dX - rc * dPi);  // bPi
        } else if (MODE == 2) {
          dst[off] = d;
          eA[off] = eA[off] + vs * eB[off] / zb[b * Tn + row];
        } else {
          dst[off] = d;
        }
      }
    }
  }
}

// Final LayerNorm (fp32 out, in-place capable)
__global__ void __launch_bounds__(256) ln_f32_kernel(
    const float* src, const float* __restrict__ w,
    float* dst, const float* __restrict__ cst, int alpha_idx) {
  const int row = blockIdx.x;
  const int tid = threadIdx.x;
  const float alpha = cst[alpha_idx];
  const float* x = src + (size_t)row * Cn;
  float v0 = alpha * x[tid];
  float v1 = alpha * x[tid + 256];
  float v2 = alpha * x[tid + 512];
  __shared__ float red[256];
  red[tid] = v0 + v1 + v2;
  __syncthreads();
  for (int off = 128; off > 0; off >>= 1) {
    if (tid < off) red[tid] += red[tid + off];
    __syncthreads();
  }
  const float m = red[0] * (1.0f / Cn);
  __syncthreads();
  const float d0 = v0 - m, d1 = v1 - m, d2 = v2 - m;
  red[tid] = d0 * d0 + d1 * d1 + d2 * d2;
  __syncthreads();
  for (int off = 128; off > 0; off >>= 1) {
    if (tid < off) red[tid] += red[tid + off];
    __syncthreads();
  }
  const float rstd = rsqrtf(red[0] * (1.0f / Cn) + LNEPS);
  float* y = dst + (size_t)row * Cn;
  y[tid]       = d0 * rstd * w[tid];
  y[tid + 256] = d1 * rstd * w[tid + 256];
  y[tid + 512] = d2 * rstd * w[tid + 512];
}

extern "C" void kernel_launch(void* const* d_in, const int* in_sizes, int n_in,
                              void* d_out, int out_size, void* d_ws, size_t ws_size,
                              hipStream_t stream) {
  (void)in_sizes; (void)n_in; (void)out_size;
  const float* Xk  = (const float*)d_in[0];
  const float* Pk  = (const float*)d_in[1];
  const float* lw  = (const float*)d_in[2];
  const float* lvw = (const float*)d_in[3];
  const int*   kp  = (const int*)d_in[4];

  float* Xo = (float*)d_out;        // X state in d_out[0:BTC]
  float* Po = Xo + NBTC;            // Pi state in d_out[BTC:2BTC]

  char* wp = (char*)d_ws;
  float*  bX  = (float*)wp;  wp += NBTC * sizeof(float);
  float*  bPi = (float*)wp;  wp += NBTC * sizeof(float);
  f16_t*  XnF = (f16_t*)wp;  wp += NBTC * sizeof(f16_t);
  bf16_t* Xnb = (bf16_t*)wp; wp += NBTC * sizeof(bf16_t);
  ushort* Ehp = (ushort*)wp; wp += (size_t)Bn * NTRI * 16384 * sizeof(ushort);
  ushort* XTh = (ushort*)wp; wp += NBTC * sizeof(ushort);
  float*  zb  = (float*)wp;  wp += (size_t)Bn * Tn * sizeof(float);
  float*  sv  = (float*)wp;  wp += (size_t)Bn * Tn * sizeof(float);
  float*  cst = (float*)wp;  wp += 256;
  const size_t need = (size_t)(wp - (char*)d_ws);
  if (ws_size < need) {
    fprintf(stderr, "[kernel] ws too small: %zu < %zu\n", ws_size, need);
    return;
  }

  const dim3 b256(256);
  const dim3 gLN(Bn * Tn);
  const dim3 gXT(Tn / 64, Cn / 64, Bn);      // (32,12,4)
  const dim3 gZ(272, Bn);                    // causal 128x64 tiles x batch
  const dim3 gW(16, 16, Bn);                 // wbuild (skips upper)
  const dim3 gCore(Cn / 64, Tn / 128, Bn);   // (12,16,4) = 768 blocks
  const float rc = (float)cos(2.0), rs = (float)sin(2.0);   // theta = 2*XI*h

  prep_consts<<<1, 1, 0, stream>>>(kp, cst);

  // ---- Stage A: X-side = Xk, p = Pk (lam*Lam = 1) ----
  ln_dual_kernel<<<gLN, b256, 0, stream>>>(Xk, lw, XnF, Xnb, zb, cst, 6);
  xt_kernel<<<gXT, b256, 0, stream>>>((const ushort*)Xnb, XTh);
  zpass_mfma<<<gZ, b256, 0, stream>>>(XnF, Ehp, zb);
  sv_kernel<<<gLN, b256, 0, stream>>>(Pk, zb, sv, cst, 6);
  wbuild_kernel<<<gW, b256, 0, stream>>>(Ehp, sv);
  corepass_mfma<0><<<gCore, b256, 0, stream>>>(Ehp, XTh, Pk, Po, cst, 0, 0,
      (float*)Xk, nullptr, bX, nullptr, zb, 6, rc, rs);

  // ---- Stage B: X-side = bX, Pi-side = Po; fused velupd-B + rotation ----
  ln_dual_kernel<<<gLN, b256, 0, stream>>>(bX, lw, XnF, Xnb, zb, cst, 6);
  xt_kernel<<<gXT, b256, 0, stream>>>((const ushort*)Xnb, XTh);
  zpass_mfma<<<gZ, b256, 0, stream>>>(XnF, Ehp, zb);
  sv_kernel<<<gLN, b256, 0, stream>>>(Po, zb, sv, cst, 3);
  wbuild_kernel<<<gW, b256, 0, stream>>>(Ehp, sv);
  corepass_mfma<1><<<gCore, b256, 0, stream>>>(Ehp, XTh, Pk, bPi, cst, 0, 2,
      (float*)Xk, Po, bX, Xo, zb, 3, rc, rs);

  // ---- Stage C: X-side = bX, Pi-side = Po; fused velupd-C ----
  ln_dual_kernel<<<gLN, b256, 0, stream>>>(bX, lw, XnF, Xnb, zb, cst, 6);
  xt_kernel<<<gXT, b256, 0, stream>>>((const ushort*)Xnb, XTh);
  zpass_mfma<<<gZ, b256, 0, stream>>>(XnF, Ehp, zb);
  sv_kernel<<<gLN, b256, 0, stream>>>(Po, zb, sv, cst, 3);
  wbuild_kernel<<<gW, b256, 0, stream>>>(Ehp, sv);
  corepass_mfma<2><<<gCore, b256, 0, stream>>>(Ehp, XTh, bPi, bPi, cst, 6, 2,
      Xo, Po, nullptr, nullptr, zb, 3, rc, rs);

  // ---- Stage D: X-side = Xo, p = lam_tk1*bPi ----
  ln_dual_kernel<<<gLN, b256, 0, stream>>>(Xo, lw, XnF, Xnb, zb, cst, 6);
  xt_kernel<<<gXT, b256, 0, stream>>>((const ushort*)Xnb, XTh);
  zpass_mfma<<<gZ, b256, 0, stream>>>(XnF, Ehp, zb);
  sv_kernel<<<gLN, b256, 0, stream>>>(bPi, zb, sv, cst, 5);
  wbuild_kernel<<<gW, b256, 0, stream>>>(Ehp, sv);
  corepass_mfma<3><<<gCore, b256, 0, stream>>>(Ehp, XTh, Po, Po, cst, 6, 4,
      nullptr, nullptr, nullptr, nullptr, zb, 6, rc, rs);

  // ---- Final: Pk1 = LN(lam_tk1 * Pi) * ln_v_w (in place on Po) ----
  ln_f32_kernel<<<gLN, b256, 0, stream>>>(Po, lvw, Po, cst, 5);
}

// Round 8
// 649.571 us; speedup vs baseline: 5.6449x; 1.0622x over previous
//
#include <hip/hip_runtime.h>
#include <hip/hip_bf16.h>
#include <cstdio>
#include <cmath>

// Problem constants (B,T,C,NH fixed by the reference)
constexpr int   Bn = 4;
constexpr int   Tn = 2048;
constexpr int   Cn = 768;
constexpr float COEF  = 0.125f / 12.0f;   // SCALE / NH
constexpr float EPSZ  = 1e-8f;
constexpr float LNEPS = 1e-5f;
constexpr int   NTRI  = 136;              // triangular 128-tiles per batch
#define NBTC ((size_t)Bn * Tn * Cn)

typedef __bf16 bf16_t;
typedef _Float16 f16_t;
typedef bf16_t bf16x8 __attribute__((ext_vector_type(8)));
typedef f16_t  f16x8  __attribute__((ext_vector_type(8)));
typedef float  f32x4  __attribute__((ext_vector_type(4)));
typedef ushort u16x8  __attribute__((ext_vector_type(8)));

// async global->LDS, 16B per lane. LDS dest is wave-uniform base + lane*16.
__device__ __forceinline__ void gload16(const void* g, void* l) {
  __builtin_amdgcn_global_load_lds(
      (const __attribute__((address_space(1))) unsigned int*)g,
      (__attribute__((address_space(3))) unsigned int*)l,
      16, 0, 0);
}

__device__ __forceinline__ ushort bf16_bits(float f) {
  bf16_t h = (bf16_t)f;
  return __builtin_bit_cast(ushort, h);
}
__device__ __forceinline__ float bits_to_f(ushort u) {
  return (float)__builtin_bit_cast(bf16_t, u);
}

// cst[] indices: 0 Lam_tk, 1 lam_tk, 2 Lam_tbar, 3 lam_tbar, 4 Lam_tk1, 5 lam_tk1, 6 = 1.0
__global__ void prep_consts(const int* kp, float* cst) {
  if (threadIdx.x == 0 && blockIdx.x == 0) {
    float tk = 1.0f + (float)(*kp);
    float tb = tk + 0.5f;
    float t1 = tk + 1.0f;
    cst[0] = tk * tk * tk; cst[1] = 1.0f / cst[0];
    cst[2] = tb * tb * tb; cst[3] = 1.0f / cst[2];
    cst[4] = t1 * t1 * t1; cst[5] = 1.0f / cst[4];
    cst[6] = 1.0f;
  }
}

// LayerNorm of (alpha*src) with weight w -> fp16 (gram operand) + bf16
// (corepass operand) outputs. Also zeroes zbuf[row] for zpass atomics.
__global__ void __launch_bounds__(256) ln_dual_kernel(
    const float* __restrict__ src, const float* __restrict__ w,
    f16_t* __restrict__ outF, bf16_t* __restrict__ outB,
    float* __restrict__ zbuf, const float* __restrict__ cst, int alpha_idx) {
  const int row = blockIdx.x;
  const int tid = threadIdx.x;
  const float alpha = cst[alpha_idx];
  const float* x = src + (size_t)row * Cn;
  float v0 = alpha * x[tid];
  float v1 = alpha * x[tid + 256];
  float v2 = alpha * x[tid + 512];
  __shared__ float red[256];
  red[tid] = v0 + v1 + v2;
  __syncthreads();
  for (int off = 128; off > 0; off >>= 1) {
    if (tid < off) red[tid] += red[tid + off];
    __syncthreads();
  }
  const float m = red[0] * (1.0f / Cn);
  __syncthreads();
  const float d0 = v0 - m, d1 = v1 - m, d2 = v2 - m;
  red[tid] = d0 * d0 + d1 * d1 + d2 * d2;
  __syncthreads();
  for (int off = 128; off > 0; off >>= 1) {
    if (tid < off) red[tid] += red[tid + off];
    __syncthreads();
  }
  const float rstd = rsqrtf(red[0] * (1.0f / Cn) + LNEPS);
  const size_t base = (size_t)row * Cn;
  float f0 = d0 * rstd * w[tid];
  float f1 = d1 * rstd * w[tid + 256];
  float f2 = d2 * rstd * w[tid + 512];
  outF[base + tid]       = (f16_t)f0;  outB[base + tid]       = (bf16_t)f0;
  outF[base + tid + 256] = (f16_t)f1;  outB[base + tid + 256] = (bf16_t)f1;
  outF[base + tid + 512] = (f16_t)f2;  outB[base + tid + 512] = (bf16_t)f2;
  if (tid == 0) zbuf[row] = 0.0f;
}

// Transpose Xnb [b][s][c] -> XT [b][c][s] (bf16). grid (Tn/64, Cn/64, Bn).
__global__ void __launch_bounds__(256) xt_kernel(
    const ushort* __restrict__ Xh, ushort* __restrict__ XT) {
  const int b = blockIdx.z;
  const int s0 = blockIdx.x * 64, c0 = blockIdx.y * 64;
  const int tid = threadIdx.x;
  __shared__ ushort t[64][68];
  const ushort* src = Xh + (size_t)b * Tn * Cn;
  ushort* dst = XT + (size_t)b * Cn * Tn;
  #pragma unroll
  for (int p = 0; p < 4; ++p) {
    const int r = p * 16 + (tid >> 4);
    const int c = (tid & 15) * 4;
    const ushort4 v = *(const ushort4*)&src[(size_t)(s0 + r) * Cn + c0 + c];
    *(ushort4*)&t[r][c] = v;
  }
  __syncthreads();
  #pragma unroll
  for (int p = 0; p < 4; ++p) {
    const int cc = p * 16 + (tid >> 4);
    const int ss = (tid & 15) * 4;
    ushort4 o;
    o.x = t[ss + 0][cc]; o.y = t[ss + 1][cc];
    o.z = t[ss + 2][cc]; o.w = t[ss + 3][cc];
    *(ushort4*)&dst[(size_t)(c0 + cc) * Tn + s0 + ss] = o;
  }
}

// Causal gram, 128x64 tile, single-fp16 MFMA, K=64 double-slab chunks.
// E = exp(clip(S*COEF)) stored single-bf16 into packed 128x128 triangular
// tiles (pair-packed uint stores). Row sums -> atomicAdd zbuf.
// grid = (272, Bn), block 256.
__global__ void __launch_bounds__(256) zpass_mfma(
    const f16_t* __restrict__ XnF,
    ushort* __restrict__ Ehp, float* __restrict__ zbuf) {
  const int b = blockIdx.y;
  const int l = blockIdx.x;
  int it = (int)(0.5f * (sqrtf(4.0f * (float)l + 1.0f) - 1.0f));
  while ((it + 1) * (it + 2) <= l) ++it;
  while (it * (it + 1) > l) --it;
  const int js = l - it * (it + 1);          // 0 .. 2it+1
  const int t0 = it * 128, s0 = js * 64;
  const int tri = it * (it + 1) / 2 + (js >> 1);
  const int colTileBase = (js & 1) * 64;

  const int tid  = threadIdx.x;
  const int lane = tid & 63;
  const int wv   = tid >> 6;
  const int wr   = wv >> 1, wc = wv & 1;     // wave covers 64t x 32s
  const int quad = lane >> 4, l15 = lane & 15;

  const f16_t* XbF = XnF + (size_t)b * Tn * Cn;
  ushort* EhT = Ehp + ((size_t)b * NTRI + tri) * 16384;

  __shared__ f16_t Af[2][128 * 32];   // 16 KB
  __shared__ f16_t Bf[2][64 * 32];    // 8 KB

  const int srow = lane >> 2;                // 0..15
  const int scol = (lane & 3) * 8;

  f32x4 acc[4][2] = {};

  for (int c0 = 0; c0 < Cn; c0 += 64) {
    __syncthreads();                 // protect LDS while prev chunk still read
    #pragma unroll
    for (int h = 0; h < 2; ++h) {
      const int cb = c0 + h * 32;
      const int rb0 = wv * 16, rb1 = 64 + wv * 16;
      gload16(XbF + (size_t)(t0 + rb0 + srow) * Cn + cb + scol, Af[h] + rb0 * 32);
      gload16(XbF + (size_t)(t0 + rb1 + srow) * Cn + cb + scol, Af[h] + rb1 * 32);
      gload16(XbF + (size_t)(s0 + rb0 + srow) * Cn + cb + scol, Bf[h] + rb0 * 32);
    }
    __syncthreads();                 // drain vmcnt + all slabs present

    #pragma unroll
    for (int h = 0; h < 2; ++h) {
      f16x8 af[4], bf[2];
      #pragma unroll
      for (int i = 0; i < 4; ++i)
        af[i] = *(const f16x8*)&Af[h][(wr * 64 + i * 16 + l15) * 32 + quad * 8];
      #pragma unroll
      for (int j = 0; j < 2; ++j)
        bf[j] = *(const f16x8*)&Bf[h][(wc * 32 + j * 16 + l15) * 32 + quad * 8];
      #pragma unroll
      for (int i = 0; i < 4; ++i)
        #pragma unroll
        for (int j = 0; j < 2; ++j)
          acc[i][j] = __builtin_amdgcn_mfma_f32_16x16x32_f16(af[i], bf[j], acc[i][j], 0, 0, 0);
    }
  }

  float zacc[4][4];
  #pragma unroll
  for (int i = 0; i < 4; ++i)
    #pragma unroll
    for (int r = 0; r < 4; ++r) zacc[i][r] = 0.0f;

  #pragma unroll
  for (int i = 0; i < 4; ++i) {
    #pragma unroll
    for (int j = 0; j < 2; ++j) {
      const int inCol = colTileBase + wc * 32 + j * 16 + l15;
      const int gcol  = s0 + wc * 32 + j * 16 + l15;
      #pragma unroll
      for (int r = 0; r < 4; ++r) {
        const int rowL = wr * 64 + i * 16 + quad * 4 + r;
        float sV = acc[i][j][r] * COEF;
        sV = fminf(fmaxf(sV, -60.f), 60.f);
        const float e = (gcol <= t0 + rowL) ? __expf(sV) : 0.f;
        const float pe = __shfl_xor(e, 1);
        if ((lane & 1) == 0) {
          const uint pk = (uint)bf16_bits(e) | ((uint)bf16_bits(pe) << 16);
          *(uint*)&EhT[rowL * 128 + inCol] = pk;
        }
        zacc[i][r] += e;
      }
    }
  }
  #pragma unroll
  for (int i = 0; i < 4; ++i)
    #pragma unroll
    for (int r = 0; r < 4; ++r) {
      float v = zacc[i][r];
      v += __shfl_xor(v, 1);
      v += __shfl_xor(v, 2);
      v += __shfl_xor(v, 4);
      v += __shfl_xor(v, 8);
      if (l15 == 0)
        atomicAdd(&zbuf[b * Tn + t0 + wr * 64 + i * 16 + quad * 4 + r], v);
    }
}

// Finalize z (raw sum -> max(sum/T, EPS)) and compute sv = |p|^2 / (z^2 + EPS).
__global__ void __launch_bounds__(256) sv_kernel(
    const float* __restrict__ Pisrc, float* __restrict__ zbuf,
    float* __restrict__ sv, const float* __restrict__ cst, int ps_idx) {
  const int row = blockIdx.x;
  const int tid = threadIdx.x;
  const float* p = Pisrc + (size_t)row * Cn;
  const float v0 = p[tid], v1 = p[tid + 256], v2 = p[tid + 512];
  __shared__ float red[256];
  red[tid] = v0 * v0 + v1 * v1 + v2 * v2;
  __syncthreads();
  for (int off = 128; off > 0; off >>= 1) {
    if (tid < off) red[tid] += red[tid + off];
    __syncthreads();
  }
  if (tid == 0) {
    const float ps = cst[ps_idx];
    const float a = red[0] * ps * ps;
    const float zf = fmaxf(zbuf[row] * (1.0f / Tn), EPSZ);
    zbuf[row] = zf;
    sv[row] = a / (zf * zf + EPSZ);
  }
}

// In-place W-build: E[t,s] *= (sv[t] + sv[s] - 2), packed single-bf16 tiles.
// grid = (16 s-tiles, 16 t-tiles, Bn); skip strictly-upper tiles.
__global__ void __launch_bounds__(256) wbuild_kernel(
    ushort* __restrict__ Ehp, const float* __restrict__ sv) {
  const int st = blockIdx.x, it = blockIdx.y, b = blockIdx.z;
  if (st > it) return;
  const int tri = it * (it + 1) / 2 + st;
  ushort* EhT = Ehp + ((size_t)b * NTRI + tri) * 16384;
  const float* svB = sv + b * Tn;

  const int tid = threadIdx.x;
  const int r  = tid >> 1;            // 0..127
  const int ch = (tid & 1) * 64;      // col half
  const float svt2 = svB[it * 128 + r] - 2.0f;
  const int base = r * 128 + ch;
  #pragma unroll
  for (int v = 0; v < 8; ++v) {
    u16x8 h8 = *(const u16x8*)&EhT[base + v * 8];
    const float4 sa = *(const float4*)(svB + st * 128 + ch + v * 8);
    const float4 sb = *(const float4*)(svB + st * 128 + ch + v * 8 + 4);
    const float ss[8] = {sa.x, sa.y, sa.z, sa.w, sb.x, sb.y, sb.z, sb.w};
    u16x8 nh;
    #pragma unroll
    for (int q = 0; q < 8; ++q) {
      const float w = bits_to_f(h8[q]) * (svt2 + ss[q]);
      nh[q] = bf16_bits(w);
    }
    *(u16x8*)&EhT[base + v * 8] = nh;
  }
}

// core GEMM + fused elementwise epilogues. K=64 double-slab chunks.
// dst = src*cst[ss_idx] + coef * W @ Xn, then per MODE (see launches).
// Tile 128t x 64c; 1D grid of 768 blocks, XCD-affinity swizzled so the 12
// c-blocks sharing a W strip land on the same XCD (id % 8 residue).
template <int MODE>
__global__ void __launch_bounds__(256) corepass_mfma(
    const ushort* __restrict__ Whp, const ushort* __restrict__ XT,
    const float* src, float* dst,
    const float* __restrict__ cst, int ss_idx, int lam_idx,
    float* eA, float* eB, float* eC, float* eD,
    const float* __restrict__ zb, int vel_idx, float rc, float rs) {
  // decode: id = r8 + 8*(g>>3) + 64*ic, g = (it<<2)|b
  const int id = blockIdx.x;
  const int r8 = id & 7;
  const int m  = id >> 3;
  const int g  = ((m & 7) << 3) | r8;
  const int ic = m >> 3;                 // 0..11
  const int it = g >> 2;                 // 0..15
  const int b  = g & 3;                  // 0..3
  const int t0 = it * 128, c0 = ic * 64;

  const int tid  = threadIdx.x;
  const int lane = tid & 63;
  const int wv   = tid >> 6;
  const int wr   = wv >> 1, wc = wv & 1;   // wave covers 64t x 32c
  const int quad = lane >> 4, l15 = lane & 15;

  const ushort* WhB = Whp + (size_t)b * NTRI * 16384;
  const ushort* XTb = XT + (size_t)b * Cn * Tn;

  __shared__ ushort Ah[2][128 * 32];   // W slabs  (16 KB)
  __shared__ ushort Bh[2][64 * 32];    // X^T slabs (8 KB)

  const int srow = lane >> 2;
  const int scol = (lane & 3) * 8;
  const int triBase = it * (it + 1) / 2;

  f32x4 acc[4][2] = {};
  const int chunks = (it + 1) * 2;           // 64-k chunks
  for (int kc = 0; kc < chunks; ++kc) {
    const int ss0 = kc * 64;
    const int stile = kc >> 1, soff = (kc & 1) * 64;
    const ushort* tileB = WhB + (size_t)(triBase + stile) * 16384 + soff;

    __syncthreads();                 // prev chunk's LDS reads done
    #pragma unroll
    for (int h = 0; h < 2; ++h) {
      const ushort* tileH = tileB + h * 32;
      const int rb0 = wv * 16, rb1 = 64 + wv * 16;
      gload16(tileH + (size_t)(rb0 + srow) * 128 + scol, Ah[h] + rb0 * 32);
      gload16(tileH + (size_t)(rb1 + srow) * 128 + scol, Ah[h] + rb1 * 32);
      gload16(XTb + (size_t)(c0 + wv * 16 + srow) * Tn + ss0 + h * 32 + scol,
              Bh[h] + wv * 16 * 32);
    }
    __syncthreads();                 // drain vmcnt

    #pragma unroll
    for (int h = 0; h < 2; ++h) {
      bf16x8 ah[4], bh[2];
      #pragma unroll
      for (int i = 0; i < 4; ++i)
        ah[i] = *(const bf16x8*)&Ah[h][(wr * 64 + i * 16 + l15) * 32 + quad * 8];
      #pragma unroll
      for (int j = 0; j < 2; ++j)
        bh[j] = *(const bf16x8*)&Bh[h][(wc * 32 + j * 16 + l15) * 32 + quad * 8];
      #pragma unroll
      for (int i = 0; i < 4; ++i)
        #pragma unroll
        for (int j = 0; j < 2; ++j)
          acc[i][j] = __builtin_amdgcn_mfma_f32_16x16x32_bf16(ah[i], bh[j], acc[i][j], 0, 0, 0);
    }
  }

  const float coef = 0.5f * cst[lam_idx] * (1.0f / (2.0f * Tn));
  const float ssc = cst[ss_idx];
  const float vs = 0.5f * cst[vel_idx];
  #pragma unroll
  for (int i = 0; i < 4; ++i) {
    #pragma unroll
    for (int j = 0; j < 2; ++j) {
      const int col = c0 + wc * 32 + j * 16 + l15;
      #pragma unroll
      for (int r = 0; r < 4; ++r) {
        const int row = t0 + wr * 64 + i * 16 + quad * 4 + r;
        const size_t off = ((size_t)b * Tn + row) * Cn + col;
        const float srcv = src[off];
        const float d = srcv * ssc + coef * acc[i][j][r];
        if (MODE == 0) {
          dst[off] = d;
          eC[off] = eA[off] + vs * srcv / zb[b * Tn + row];
        } else if (MODE == 1) {
          const float z  = zb[b * Tn + row];
          const float po = eB[off];
          const float xo = eA[off] + vs * po / z;
          const float bx = eC[off];
          const float dX = xo - bx, dPi = po - d;
          const float sX = xo + bx, sPi = po + d;
          eD[off]  = 0.5f * (sX + rc * dX + rs * dPi);   // Xo
          eB[off]  = 0.5f * (sPi - rs * dX + rc * dPi);  // Po
          eC[off]  = 0.5f * (sX - rc * dX - rs * dPi);   // bX
          dst[off] = 0.5f * (sPi + rs * dX - rc * dPi);  // bPi
        } else if (MODE == 2) {
          dst[off] = d;
          eA[off] = eA[off] + vs * eB[off] / zb[b * Tn + row];
        } else {
          dst[off] = d;
        }
      }
    }
  }
}

// Final LayerNorm (fp32 out, in-place capable)
__global__ void __launch_bounds__(256) ln_f32_kernel(
    const float* src, const float* __restrict__ w,
    float* dst, const float* __restrict__ cst, int alpha_idx) {
  const int row = blockIdx.x;
  const int tid = threadIdx.x;
  const float alpha = cst[alpha_idx];
  const float* x = src + (size_t)row * Cn;
  float v0 = alpha * x[tid];
  float v1 = alpha * x[tid + 256];
  float v2 = alpha * x[tid + 512];
  __shared__ float red[256];
  red[tid] = v0 + v1 + v2;
  __syncthreads();
  for (int off = 128; off > 0; off >>= 1) {
    if (tid < off) red[tid] += red[tid + off];
    __syncthreads();
  }
  const float m = red[0] * (1.0f / Cn);
  __syncthreads();
  const float d0 = v0 - m, d1 = v1 - m, d2 = v2 - m;
  red[tid] = d0 * d0 + d1 * d1 + d2 * d2;
  __syncthreads();
  for (int off = 128; off > 0; off >>= 1) {
    if (tid < off) red[tid] += red[tid + off];
    __syncthreads();
  }
  const float rstd = rsqrtf(red[0] * (1.0f / Cn) + LNEPS);
  float* y = dst + (size_t)row * Cn;
  y[tid]       = d0 * rstd * w[tid];
  y[tid + 256] = d1 * rstd * w[tid + 256];
  y[tid + 512] = d2 * rstd * w[tid + 512];
}

extern "C" void kernel_launch(void* const* d_in, const int* in_sizes, int n_in,
                              void* d_out, int out_size, void* d_ws, size_t ws_size,
                              hipStream_t stream) {
  (void)in_sizes; (void)n_in; (void)out_size;
  const float* Xk  = (const float*)d_in[0];
  const float* Pk  = (const float*)d_in[1];
  const float* lw  = (const float*)d_in[2];
  const float* lvw = (const float*)d_in[3];
  const int*   kp  = (const int*)d_in[4];

  float* Xo = (float*)d_out;        // X state in d_out[0:BTC]
  float* Po = Xo + NBTC;            // Pi state in d_out[BTC:2BTC]

  char* wp = (char*)d_ws;
  float*  bX  = (float*)wp;  wp += NBTC * sizeof(float);
  float*  bPi = (float*)wp;  wp += NBTC * sizeof(float);
  f16_t*  XnF = (f16_t*)wp;  wp += NBTC * sizeof(f16_t);
  bf16_t* Xnb = (bf16_t*)wp; wp += NBTC * sizeof(bf16_t);
  ushort* Ehp = (ushort*)wp; wp += (size_t)Bn * NTRI * 16384 * sizeof(ushort);
  ushort* XTh = (ushort*)wp; wp += NBTC * sizeof(ushort);
  float*  zb  = (float*)wp;  wp += (size_t)Bn * Tn * sizeof(float);
  float*  sv  = (float*)wp;  wp += (size_t)Bn * Tn * sizeof(float);
  float*  cst = (float*)wp;  wp += 256;
  const size_t need = (size_t)(wp - (char*)d_ws);
  if (ws_size < need) {
    fprintf(stderr, "[kernel] ws too small: %zu < %zu\n", ws_size, need);
    return;
  }

  const dim3 b256(256);
  const dim3 gLN(Bn * Tn);
  const dim3 gXT(Tn / 64, Cn / 64, Bn);      // (32,12,4)
  const dim3 gZ(272, Bn);                    // causal 128x64 tiles x batch
  const dim3 gW(16, 16, Bn);                 // wbuild (skips upper)
  const dim3 gCore(768);                     // XCD-swizzled 1D grid
  const float rc = (float)cos(2.0), rs = (float)sin(2.0);   // theta = 2*XI*h

  prep_consts<<<1, 1, 0, stream>>>(kp, cst);

  // ---- Stage A: X-side = Xk, p = Pk (lam*Lam = 1) ----
  ln_dual_kernel<<<gLN, b256, 0, stream>>>(Xk, lw, XnF, Xnb, zb, cst, 6);
  xt_kernel<<<gXT, b256, 0, stream>>>((const ushort*)Xnb, XTh);
  zpass_mfma<<<gZ, b256, 0, stream>>>(XnF, Ehp, zb);
  sv_kernel<<<gLN, b256, 0, stream>>>(Pk, zb, sv, cst, 6);
  wbuild_kernel<<<gW, b256, 0, stream>>>(Ehp, sv);
  corepass_mfma<0><<<gCore, b256, 0, stream>>>(Ehp, XTh, Pk, Po, cst, 0, 0,
      (float*)Xk, nullptr, bX, nullptr, zb, 6, rc, rs);

  // ---- Stage B: X-side = bX, Pi-side = Po; fused velupd-B + rotation ----
  ln_dual_kernel<<<gLN, b256, 0, stream>>>(bX, lw, XnF, Xnb, zb, cst, 6);
  xt_kernel<<<gXT, b256, 0, stream>>>((const ushort*)Xnb, XTh);
  zpass_mfma<<<gZ, b256, 0, stream>>>(XnF, Ehp, zb);
  sv_kernel<<<gLN, b256, 0, stream>>>(Po, zb, sv, cst, 3);
  wbuild_kernel<<<gW, b256, 0, stream>>>(Ehp, sv);
  corepass_mfma<1><<<gCore, b256, 0, stream>>>(Ehp, XTh, Pk, bPi, cst, 0, 2,
      (float*)Xk, Po, bX, Xo, zb, 3, rc, rs);

  // ---- Stage C: X-side = bX, Pi-side = Po; fused velupd-C ----
  ln_dual_kernel<<<gLN, b256, 0, stream>>>(bX, lw, XnF, Xnb, zb, cst, 6);
  xt_kernel<<<gXT, b256, 0, stream>>>((const ushort*)Xnb, XTh);
  zpass_mfma<<<gZ, b256, 0, stream>>>(XnF, Ehp, zb);
  sv_kernel<<<gLN, b256, 0, stream>>>(Po, zb, sv, cst, 3);
  wbuild_kernel<<<gW, b256, 0, stream>>>(Ehp, sv);
  corepass_mfma<2><<<gCore, b256, 0, stream>>>(Ehp, XTh, bPi, bPi, cst, 6, 2,
      Xo, Po, nullptr, nullptr, zb, 3, rc, rs);

  // ---- Stage D: X-side = Xo, p = lam_tk1*bPi ----
  ln_dual_kernel<<<gLN, b256, 0, stream>>>(Xo, lw, XnF, Xnb, zb, cst, 6);
  xt_kernel<<<gXT, b256, 0, stream>>>((const ushort*)Xnb, XTh);
  zpass_mfma<<<gZ, b256, 0, stream>>>(XnF, Ehp, zb);
  sv_kernel<<<gLN, b256, 0, stream>>>(bPi, zb, sv, cst, 5);
  wbuild_kernel<<<gW, b256, 0, stream>>>(Ehp, sv);
  corepass_mfma<3><<<gCore, b256, 0, stream>>>(Ehp, XTh, Po, Po, cst, 6, 4,
      nullptr, nullptr, nullptr, nullptr, zb, 6, rc, rs);

  // ---- Final: Pk1 = LN(lam_tk1 * Pi) * ln_v_w (in place on Po) ----
  ln_f32_kernel<<<gLN, b256, 0, stream>>>(Po, lvw, Po, cst, 5);
}